// Round 3
// baseline (421.683 us; speedup 1.0000x reference)
//
#include <hip/hip_runtime.h>
#include <math.h>

// Shapes (fixed): L=512 B=4 D=1024 H=16 DH=64 FF=4096 HP=32 K=256, LK=768

typedef __bf16 bf16x8 __attribute__((ext_vector_type(8)));
typedef float f32x4 __attribute__((ext_vector_type(4)));

__device__ __forceinline__ unsigned short f2bf(float f) {
  unsigned u = __float_as_uint(f);
  u = (u + 0x7fffu + ((u >> 16) & 1u)) >> 16;
  return (unsigned short)u;
}
__device__ __forceinline__ float bf2f(unsigned short s) {
  return __uint_as_float(((unsigned)s) << 16);
}

__device__ __forceinline__ void gload_lds16(const void* g, void* l) {
  __builtin_amdgcn_global_load_lds(
      (__attribute__((address_space(1))) void*)g,
      (__attribute__((address_space(3))) void*)l, 16, 0, 0);
}

// ------------- ALL weight transposes f32 -> bf16 in one launch ---------------
// wq/wk/wv -> qkvT (3x 1024x1024), wo -> woT, fc1 -> fc1T (4096x1024),
// fc2 -> fc2T (1024x4096), w1 -> w1T (64x1024)
__global__ __launch_bounds__(256) void transpose_all(
    const float* __restrict__ wq, const float* __restrict__ wk, const float* __restrict__ wv,
    const float* __restrict__ wo, const float* __restrict__ fc1, const float* __restrict__ fc2,
    const float* __restrict__ w1,
    unsigned short* __restrict__ qkvT, unsigned short* __restrict__ woT,
    unsigned short* __restrict__ fc1T, unsigned short* __restrict__ fc2T,
    unsigned short* __restrict__ w1T) {
  int id = blockIdx.x;
  const float* W; unsigned short* WT; int Kd, Nd, n0, k0;
  if (id < 3072) {            // wq, wk, wv
    int which = id >> 10, lid = id & 1023;
    W = which == 0 ? wq : (which == 1 ? wk : wv);
    WT = qkvT + (long)which * 1024 * 1024;
    Kd = 1024; Nd = 1024; n0 = (lid & 31) * 32; k0 = (lid >> 5) * 32;
  } else if (id < 4096) {     // wo
    int lid = id - 3072;
    W = wo; WT = woT; Kd = 1024; Nd = 1024;
    n0 = (lid & 31) * 32; k0 = (lid >> 5) * 32;
  } else if (id < 8192) {     // fc1 (K=1024, N=4096)
    int lid = id - 4096;
    W = fc1; WT = fc1T; Kd = 1024; Nd = 4096;
    n0 = (lid & 127) * 32; k0 = (lid >> 7) * 32;
  } else if (id < 12288) {    // fc2 (K=4096, N=1024)
    int lid = id - 8192;
    W = fc2; WT = fc2T; Kd = 4096; Nd = 1024;
    n0 = (lid & 31) * 32; k0 = (lid >> 5) * 32;
  } else {                    // w1 (K=1024, N=64)
    int lid = id - 12288;
    W = w1; WT = w1T; Kd = 1024; Nd = 64;
    n0 = (lid & 1) * 32; k0 = (lid >> 1) * 32;
  }
  __shared__ float tile[32][33];
  const int tx = threadIdx.x, ty = threadIdx.y;  // 32 x 8
#pragma unroll
  for (int i = 0; i < 32; i += 8)
    tile[ty + i][tx] = W[(long)(k0 + ty + i) * Nd + n0 + tx];
  __syncthreads();
#pragma unroll
  for (int i = 0; i < 32; i += 8)
    WT[(long)(n0 + ty + i) * Kd + k0 + tx] = f2bf(tile[tx][ty + i]);
}

// ---------------- LayerNorm (f32 in, bf16 out), row = 1024 -------------------
__global__ __launch_bounds__(256) void ln_bf16(
    const float* __restrict__ X, unsigned short* __restrict__ Y,
    const float* __restrict__ g, const float* __restrict__ bb) {
  const int row = blockIdx.x, t = threadIdx.x;
  const float* xr = X + (long)row * 1024;
  float v[4]; float s = 0.f, ss = 0.f;
#pragma unroll
  for (int i = 0; i < 4; i++) { v[i] = xr[t + 256 * i]; s += v[i]; ss += v[i] * v[i]; }
#pragma unroll
  for (int o = 32; o > 0; o >>= 1) { s += __shfl_down(s, o); ss += __shfl_down(ss, o); }
  __shared__ float red[8];
  const int wave = t >> 6, lane = t & 63;
  if (lane == 0) { red[wave] = s; red[4 + wave] = ss; }
  __syncthreads();
  s = red[0] + red[1] + red[2] + red[3];
  ss = red[4] + red[5] + red[6] + red[7];
  const float mean = s * (1.f / 1024.f);
  const float rstd = rsqrtf(ss * (1.f / 1024.f) - mean * mean + 1e-5f);
#pragma unroll
  for (int i = 0; i < 4; i++) {
    const int c = t + 256 * i;
    Y[(long)row * 1024 + c] = f2bf((v[i] - mean) * rstd * g[c] + bb[c]);
  }
}

// -------- gather expanded rows of kv_src (bf16), rows [2048, 3072) -----------
__global__ __launch_bounds__(256) void gather_kv(unsigned short* kv, const int* __restrict__ oc) {
  int idx = blockIdx.x * 256 + threadIdx.x;  // 1024 rows * 256 ushort4 = 262144
  int col4 = idx & 255;
  int r = idx >> 8;
  int j = r >> 2, b = r & 3;
  int src = oc[b * 256 + j] * 4 + b;
  ((ushort4*)kv)[((512 + j) * 4 + b) * 256 + col4] = ((const ushort4*)kv)[src * 256 + col4];
}

// ---------------- MFMA bf16 NT GEMM, 128x128 tile, BK=32 ---------------------
// EPI: 0 = f32 out, 1 = f32 out + R, 2 = bf16 gelu(out), 3 = bf16 out
template <int EPI>
__global__ __launch_bounds__(256) void gemm_nt(
    const unsigned short* __restrict__ A, const unsigned short* __restrict__ BT,
    void* __restrict__ Cout, const float* __restrict__ R, int M, int N, int Kd) {
  __shared__ __align__(16) unsigned short As[128 * 32];
  __shared__ __align__(16) unsigned short Bs[128 * 32];
  const int t = threadIdx.x;
  const int wave = t >> 6, lane = t & 63;
  const int m0 = blockIdx.y * 128, n0 = blockIdx.x * 128;
  const int wr = wave >> 1, wc = wave & 1;
  const int lr = lane & 15, lg = lane >> 4;

  f32x4 acc[4][4] = {};

  const int srow = 32 * wave + (lane >> 2);
  const int schunk = (lane & 3) * 8;
  const unsigned short* Ag = A + (long)(m0 + srow) * Kd + schunk;
  const unsigned short* Bg = BT + (long)(n0 + srow) * Kd + schunk;
  unsigned short* AsW = &As[(32 * wave) * 32];
  unsigned short* BsW = &Bs[(32 * wave) * 32];

  for (int k0 = 0; k0 < Kd; k0 += 32) {
    __syncthreads();
    gload_lds16(Ag + k0, AsW);
    gload_lds16(Ag + k0 + 16 * (long)Kd, AsW + 16 * 32);
    gload_lds16(Bg + k0, BsW);
    gload_lds16(Bg + k0 + 16 * (long)Kd, BsW + 16 * 32);
    asm volatile("s_waitcnt vmcnt(0)" ::: "memory");
    __syncthreads();

    bf16x8 af[4], bfr[4];
#pragma unroll
    for (int mf = 0; mf < 4; mf++)
      af[mf] = *(const bf16x8*)&As[(64 * wr + 16 * mf + lr) * 32 + lg * 8];
#pragma unroll
    for (int nf = 0; nf < 4; nf++)
      bfr[nf] = *(const bf16x8*)&Bs[(64 * wc + 16 * nf + lr) * 32 + lg * 8];
#pragma unroll
    for (int mf = 0; mf < 4; mf++)
#pragma unroll
      for (int nf = 0; nf < 4; nf++)
        acc[mf][nf] = __builtin_amdgcn_mfma_f32_16x16x32_bf16(af[mf], bfr[nf], acc[mf][nf], 0, 0, 0);
  }

#pragma unroll
  for (int mf = 0; mf < 4; mf++)
#pragma unroll
    for (int nf = 0; nf < 4; nf++)
#pragma unroll
      for (int r = 0; r < 4; r++) {
        const int row = m0 + 64 * wr + 16 * mf + 4 * lg + r;
        const int col = n0 + 64 * wc + 16 * nf + lr;
        const long off = (long)row * N + col;
        float v = acc[mf][nf][r];
        if constexpr (EPI == 1) {
          ((float*)Cout)[off] = v + R[off];
        } else if constexpr (EPI == 2) {
          float gl = 0.5f * v * (1.0f + erff(v * 0.70710678118654752f));
          ((unsigned short*)Cout)[off] = f2bf(gl);
        } else if constexpr (EPI == 3) {
          ((unsigned short*)Cout)[off] = f2bf(v);
        } else {
          ((float*)Cout)[off] = v;
        }
      }
}

// ---------------- MFMA bf16 NT GEMM, 128x64 tile (for N=1024 shapes) ---------
template <int EPI>
__global__ __launch_bounds__(256) void gemm_nt64(
    const unsigned short* __restrict__ A, const unsigned short* __restrict__ BT,
    void* __restrict__ Cout, const float* __restrict__ R, int M, int N, int Kd) {
  __shared__ __align__(16) unsigned short As[128 * 32];
  __shared__ __align__(16) unsigned short Bs[64 * 32];
  const int t = threadIdx.x;
  const int wave = t >> 6, lane = t & 63;
  const int m0 = blockIdx.y * 128, n0 = blockIdx.x * 64;
  const int wr = wave >> 1, wc = wave & 1;   // 2x2 waves over (64 rows x 32 cols)
  const int lr = lane & 15, lg = lane >> 4;

  f32x4 acc[4][2] = {};

  const int srowA = 32 * wave + (lane >> 2);
  const int srowB = 16 * wave + (lane >> 2);
  const int schunk = (lane & 3) * 8;
  const unsigned short* Ag = A + (long)(m0 + srowA) * Kd + schunk;
  const unsigned short* Bg = BT + (long)(n0 + srowB) * Kd + schunk;
  unsigned short* AsW = &As[(32 * wave) * 32];
  unsigned short* BsW = &Bs[(16 * wave) * 32];

  for (int k0 = 0; k0 < Kd; k0 += 32) {
    __syncthreads();
    gload_lds16(Ag + k0, AsW);
    gload_lds16(Ag + k0 + 16 * (long)Kd, AsW + 16 * 32);
    gload_lds16(Bg + k0, BsW);
    asm volatile("s_waitcnt vmcnt(0)" ::: "memory");
    __syncthreads();

    bf16x8 af[4], bfr[2];
#pragma unroll
    for (int mf = 0; mf < 4; mf++)
      af[mf] = *(const bf16x8*)&As[(64 * wr + 16 * mf + lr) * 32 + lg * 8];
#pragma unroll
    for (int nf = 0; nf < 2; nf++)
      bfr[nf] = *(const bf16x8*)&Bs[(32 * wc + 16 * nf + lr) * 32 + lg * 8];
#pragma unroll
    for (int mf = 0; mf < 4; mf++)
#pragma unroll
      for (int nf = 0; nf < 2; nf++)
        acc[mf][nf] = __builtin_amdgcn_mfma_f32_16x16x32_bf16(af[mf], bfr[nf], acc[mf][nf], 0, 0, 0);
  }

#pragma unroll
  for (int mf = 0; mf < 4; mf++)
#pragma unroll
    for (int nf = 0; nf < 2; nf++)
#pragma unroll
      for (int r = 0; r < 4; r++) {
        const int row = m0 + 64 * wr + 16 * mf + 4 * lg + r;
        const int col = n0 + 32 * wc + 16 * nf + lr;
        const long off = (long)row * N + col;
        float v = acc[mf][nf][r];
        if constexpr (EPI == 1) {
          ((float*)Cout)[off] = v + R[off];
        } else if constexpr (EPI == 2) {
          float gl = 0.5f * v * (1.0f + erff(v * 0.70710678118654752f));
          ((unsigned short*)Cout)[off] = f2bf(gl);
        } else if constexpr (EPI == 3) {
          ((unsigned short*)Cout)[off] = f2bf(v);
        } else {
          ((float*)Cout)[off] = v;
        }
      }
}

// ---------------- RoPE + split to per-head layouts (bf16 QKV in) -------------
// qb:  [bh][512][64] bf16, scaled by 1/8.   kbh: [bh][768][64] bf16.
__global__ __launch_bounds__(256) void rope_split2(
    const unsigned short* __restrict__ QKV, const int* __restrict__ pos_ids,
    const int* __restrict__ oc,
    unsigned short* __restrict__ qb, unsigned short* __restrict__ kbh) {
  int idx = blockIdx.x * 256 + threadIdx.x;  // 1048576 + 1572864
  bool isq = idx < 1048576;
  int rp = isq ? idx : idx - 1048576;
  int p = rp & 511;
  int row = rp >> 9;
  int hh = p >> 5, dp = p & 31;
  int s = row >> 2, b = row & 3;
  int pos = isq ? pos_ids[b * 512 + s]
                : ((s < 512) ? pos_ids[b * 512 + s]
                             : pos_ids[b * 512 + oc[b * 256 + s - 512]]);
  const unsigned short* src = QKV + (long)row * 3072 + (isq ? 0 : 1024) + hh * 64 + dp;
  float x1 = bf2f(src[0]), x2 = bf2f(src[32]);
  float invf = exp2f((float)dp * -0.41524101186091903f);  // 10000^(-dp/32)
  float ang = (float)pos * invf;
  float sn = sinf(ang), cs = cosf(ang);
  float o1 = x1 * cs - x2 * sn, o2 = x1 * sn + x2 * cs;
  if (isq) {
    unsigned short* dst = qb + ((long)(b * 16 + hh) * 512 + s) * 64 + dp;
    dst[0] = f2bf(o1 * 0.125f); dst[32] = f2bf(o2 * 0.125f);
  } else {
    unsigned short* dst = kbh + ((long)(b * 16 + hh) * 768 + s) * 64 + dp;
    dst[0] = f2bf(o1); dst[32] = f2bf(o2);
  }
}

// ---------------- V: QKV bf16 -> vth bf16 transposed [bh][64 d][768 key] -----
__global__ __launch_bounds__(256) void v_transpose(
    const unsigned short* __restrict__ QKV, unsigned short* __restrict__ vth) {
  const int kt = blockIdx.x, bh = blockIdx.y;
  const int b = bh >> 4, h = bh & 15;
  __shared__ unsigned short tile[64][72];
  const int t = threadIdx.x;
  const int key = t >> 2, c = t & 3;
  const unsigned short* src = QKV + ((long)(kt * 64 + key) * 4 + b) * 3072 + 2048 + h * 64 + c * 16;
#pragma unroll
  for (int j = 0; j < 16; j++) tile[c * 16 + j][key] = src[j];
  __syncthreads();
  const int d = t >> 2;
  unsigned short* dst = vth + ((long)bh * 64 + d) * 768 + kt * 64 + c * 16;
  *(uint4*)dst = *(const uint4*)&tile[d][c * 16];
  *(uint4*)(dst + 8) = *(const uint4*)&tile[d][c * 16 + 8];
}

// ---------------- MFMA flash attention: block = (b,h, 64 queries) ------------
__global__ __launch_bounds__(256) void att_mfma(
    const unsigned short* __restrict__ qb, const unsigned short* __restrict__ kbh,
    const unsigned short* __restrict__ vth,
    const unsigned char* __restrict__ pad_mask, const unsigned char* __restrict__ exp_mask,
    unsigned short* __restrict__ o_bf) {
  const int bh = blockIdx.y, b = bh >> 4, h = bh & 15;
  const int q0 = blockIdx.x * 64;
  const int t = threadIdx.x, wave = t >> 6, lane = t & 63;
  const int lr = lane & 15, lg = lane >> 4;

  __shared__ __align__(16) unsigned short Qs[64][72];
  __shared__ __align__(16) unsigned short Ks[64][72];
  __shared__ __align__(16) unsigned short Vs[64][72];   // VT tile: [d][key]
  __shared__ __align__(16) unsigned short Ps[4][16][72];
  __shared__ float maskAdd[768];

  {  // stage Q once
    const int row = t >> 2, c = t & 3;
    const uint4* src = (const uint4*)(qb + ((long)bh * 512 + q0 + row) * 64 + c * 16);
    *(uint4*)&Qs[row][c * 16] = src[0];
    *(uint4*)&Qs[row][c * 16 + 8] = src[1];
  }
  for (int i = t; i < 768; i += 256)
    maskAdd[i] = ((i < 512) ? pad_mask[b * 512 + i] : exp_mask[b * 256 + i - 512]) ? -1e9f : 0.f;
  __syncthreads();

  const bf16x8 aq0 = *(const bf16x8*)&Qs[wave * 16 + lr][lg * 8];
  const bf16x8 aq1 = *(const bf16x8*)&Qs[wave * 16 + lr][32 + lg * 8];

  float m_run[4] = {-1e30f, -1e30f, -1e30f, -1e30f};
  float l_run[4] = {0.f, 0.f, 0.f, 0.f};
  f32x4 Oacc[4] = {};

  for (int kt = 0; kt < 12; ++kt) {
    __syncthreads();
    {  // stage K tile and VT tile
      const int row = t >> 2, c = t & 3;
      const uint4* ksrc = (const uint4*)(kbh + ((long)bh * 768 + kt * 64 + row) * 64 + c * 16);
      *(uint4*)&Ks[row][c * 16] = ksrc[0];
      *(uint4*)&Ks[row][c * 16 + 8] = ksrc[1];
      const uint4* vsrc = (const uint4*)(vth + ((long)bh * 64 + row) * 768 + kt * 64 + c * 16);
      *(uint4*)&Vs[row][c * 16] = vsrc[0];
      *(uint4*)&Vs[row][c * 16 + 8] = vsrc[1];
    }
    __syncthreads();

    // QK^T: S[16 q][64 key] per wave
    float sv[4][4];
#pragma unroll
    for (int nf = 0; nf < 4; nf++) {
      f32x4 z = {};
      bf16x8 b0 = *(const bf16x8*)&Ks[nf * 16 + lr][lg * 8];
      bf16x8 b1 = *(const bf16x8*)&Ks[nf * 16 + lr][32 + lg * 8];
      z = __builtin_amdgcn_mfma_f32_16x16x32_bf16(aq0, b0, z, 0, 0, 0);
      z = __builtin_amdgcn_mfma_f32_16x16x32_bf16(aq1, b1, z, 0, 0, 0);
      float ma = maskAdd[kt * 64 + nf * 16 + lr];
#pragma unroll
      for (int r = 0; r < 4; r++) sv[nf][r] = z[r] + ma;
    }
    // online softmax (row = lg*4+r within wave's 16)
    float mnew[4], scale[4], rs[4];
#pragma unroll
    for (int r = 0; r < 4; r++) {
      float tm = fmaxf(fmaxf(sv[0][r], sv[1][r]), fmaxf(sv[2][r], sv[3][r]));
      tm = fmaxf(tm, __shfl_xor(tm, 1));
      tm = fmaxf(tm, __shfl_xor(tm, 2));
      tm = fmaxf(tm, __shfl_xor(tm, 4));
      tm = fmaxf(tm, __shfl_xor(tm, 8));
      mnew[r] = fmaxf(m_run[r], tm);
      scale[r] = __expf(m_run[r] - mnew[r]);
      m_run[r] = mnew[r];
      rs[r] = 0.f;
    }
#pragma unroll
    for (int nf = 0; nf < 4; nf++)
#pragma unroll
      for (int r = 0; r < 4; r++) {
        float p = __expf(sv[nf][r] - mnew[r]);
        rs[r] += p;
        Ps[wave][lg * 4 + r][nf * 16 + lr] = f2bf(p);
      }
#pragma unroll
    for (int r = 0; r < 4; r++) {
      float x = rs[r];
      x += __shfl_xor(x, 1); x += __shfl_xor(x, 2);
      x += __shfl_xor(x, 4); x += __shfl_xor(x, 8);
      l_run[r] = l_run[r] * scale[r] + x;
#pragma unroll
      for (int nf = 0; nf < 4; nf++) Oacc[nf][r] *= scale[r];
    }
    // PV: O[16 q][64 d] += P @ V
    bf16x8 ap0 = *(const bf16x8*)&Ps[wave][lr][lg * 8];
    bf16x8 ap1 = *(const bf16x8*)&Ps[wave][lr][32 + lg * 8];
#pragma unroll
    for (int nf = 0; nf < 4; nf++) {
      bf16x8 b0 = *(const bf16x8*)&Vs[nf * 16 + lr][lg * 8];
      bf16x8 b1 = *(const bf16x8*)&Vs[nf * 16 + lr][32 + lg * 8];
      Oacc[nf] = __builtin_amdgcn_mfma_f32_16x16x32_bf16(ap0, b0, Oacc[nf], 0, 0, 0);
      Oacc[nf] = __builtin_amdgcn_mfma_f32_16x16x32_bf16(ap1, b1, Oacc[nf], 0, 0, 0);
    }
  }

#pragma unroll
  for (int r = 0; r < 4; r++) {
    float inv = 1.0f / l_run[r];
    int l = q0 + wave * 16 + lg * 4 + r;
#pragma unroll
    for (int nf = 0; nf < 4; nf++)
      o_bf[(((long)l * 4 + b) * 16 + h) * 64 + nf * 16 + lr] = f2bf(Oacc[nf][r] * inv);
  }
}

// ---------------- pair head: LN'd x @ w1 -> silu -> @ w2 ---------------------
// w1T: bf16 [64][1024] (k-contiguous rows)
__global__ __launch_bounds__(256) void pair_head(
    const unsigned short* __restrict__ pln, const unsigned short* __restrict__ w1T,
    const float* __restrict__ w2, float* __restrict__ xpi) {
  const int row = blockIdx.x, t = threadIdx.x;
  __shared__ float red[64][4];
  __shared__ float s1[64];
  const int c = t & 63, qt = t >> 6;
  const unsigned short* xr = pln + (long)row * 1024 + qt * 256;
  const unsigned short* wr = w1T + (long)c * 1024 + qt * 256;
  float acc = 0.f;
#pragma unroll 4
  for (int k = 0; k < 256; k++)
    acc += bf2f(xr[k]) * bf2f(wr[k]);
  red[c][qt] = acc;
  __syncthreads();
  if (t < 64) {
    float v = red[t][0] + red[t][1] + red[t][2] + red[t][3];
    s1[t] = v / (1.f + __expf(-v));  // silu
  }
  __syncthreads();
  if (t < 32) {
    float o = 0.f;
    for (int k = 0; k < 64; k++) o += s1[k] * w2[k * 32 + t];
    xpi[(long)row * 32 + t] = o;
  }
}

// ------------ x_pair += outer(x_p_i, x_p_j) with inline oc gather ------------
__global__ __launch_bounds__(256) void pair_update(
    const float* __restrict__ x_pair, const float* __restrict__ xpi,
    const int* __restrict__ oc, float* __restrict__ out) {
  int idx4 = blockIdx.x * 256 + threadIdx.x;  // 12582912 float4s
  int h4 = idx4 & 7;
  int lkb = idx4 >> 3;
  int b = lkb & 3;
  int lk = lkb >> 2;
  int kk = lk % 768;
  int l = lk / 768;
  int src = (kk < 512) ? kk : oc[b * 256 + kk - 512];
  float4 pv = ((const float4*)x_pair)[idx4];
  float4 a = ((const float4*)xpi)[(l * 4 + b) * 8 + h4];
  float4 bb = ((const float4*)xpi)[(src * 4 + b) * 8 + h4];
  float4 o;
  o.x = pv.x + a.x * bb.x; o.y = pv.y + a.y * bb.y;
  o.z = pv.z + a.z * bb.z; o.w = pv.w + a.w * bb.w;
  ((float4*)out)[idx4] = o;
}

// =============================== launcher ====================================
extern "C" void kernel_launch(void* const* d_in, const int* in_sizes, int n_in,
                              void* d_out, int out_size, void* d_ws, size_t ws_size,
                              hipStream_t stream) {
  const float* x        = (const float*)d_in[0];
  const float* x_pair   = (const float*)d_in[1];
  const unsigned char* pad_mask = (const unsigned char*)d_in[2];
  const unsigned char* exp_mask = (const unsigned char*)d_in[3];
  const int* pos_ids    = (const int*)d_in[4];
  const int* oc         = (const int*)d_in[5];
  const float* wq  = (const float*)d_in[6];
  const float* wk  = (const float*)d_in[7];
  const float* wv  = (const float*)d_in[8];
  const float* wo  = (const float*)d_in[9];
  const float* fc1 = (const float*)d_in[10];
  const float* fc2 = (const float*)d_in[11];
  const float* tln_g = (const float*)d_in[12];
  const float* tln_b = (const float*)d_in[13];
  const float* mln_g = (const float*)d_in[14];
  const float* mln_b = (const float*)d_in[15];
  const float* pln_g = (const float*)d_in[16];
  const float* pln_b = (const float*)d_in[17];
  const float* w1 = (const float*)d_in[18];
  const float* w2 = (const float*)d_in[19];

  char* wsp = (char*)d_ws;
  size_t off = 0;
  auto alloc = [&](size_t bytes) -> void* {
    void* p = wsp + off;
    off = (off + bytes + 255) & ~(size_t)255;
    return p;
  };
  unsigned short* qkvT = (unsigned short*)alloc(3072LL * 1024 * 2);
  unsigned short* woT  = (unsigned short*)alloc(1024LL * 1024 * 2);
  unsigned short* fc1T = (unsigned short*)alloc(4096LL * 1024 * 2);
  unsigned short* fc2T = (unsigned short*)alloc(1024LL * 4096 * 2);
  unsigned short* w1T  = (unsigned short*)alloc(64LL * 1024 * 2);
  unsigned short* kvb  = (unsigned short*)alloc(3072LL * 1024 * 2);
  unsigned short* QKVb = (unsigned short*)alloc(3072LL * 3072 * 2);
  unsigned short* qb   = (unsigned short*)alloc(64LL * 512 * 64 * 2);
  unsigned short* kbh  = (unsigned short*)alloc(64LL * 768 * 64 * 2);
  unsigned short* vth  = (unsigned short*)alloc(64LL * 64 * 768 * 2);
  unsigned short* obf  = (unsigned short*)alloc(2048LL * 1024 * 2);
  float* x1            = (float*)alloc(2048LL * 1024 * 4);
  unsigned short* h2   = (unsigned short*)alloc(2048LL * 1024 * 2);
  unsigned short* gbf  = (unsigned short*)alloc(2048LL * 4096 * 2);
  unsigned short* plnb = (unsigned short*)alloc(2048LL * 1024 * 2);
  float* xpi           = (float*)alloc(2048LL * 32 * 4);
  (void)ws_size; (void)in_sizes; (void)n_in; (void)out_size;

  dim3 tb(32, 8);
  transpose_all<<<12352, tb, 0, stream>>>(wq, wk, wv, wo, fc1, fc2, w1,
                                          qkvT, woT, fc1T, fc2T, w1T);

  ln_bf16<<<2048, 256, 0, stream>>>(x, kvb, tln_g, tln_b);
  gather_kv<<<1024, 256, 0, stream>>>(kvb, oc);

  gemm_nt<3><<<dim3(24, 24), 256, 0, stream>>>(kvb, qkvT, QKVb, nullptr, 3072, 3072, 1024);

  rope_split2<<<10240, 256, 0, stream>>>(QKVb, pos_ids, oc, qb, kbh);
  v_transpose<<<dim3(12, 64), 256, 0, stream>>>(QKVb, vth);

  att_mfma<<<dim3(8, 64), 256, 0, stream>>>(qb, kbh, vth, pad_mask, exp_mask, obf);

  gemm_nt64<1><<<dim3(16, 16), 256, 0, stream>>>(obf, woT, x1, x, 2048, 1024, 1024);

  ln_bf16<<<2048, 256, 0, stream>>>(x1, h2, mln_g, mln_b);
  gemm_nt<2><<<dim3(32, 16), 256, 0, stream>>>(h2, fc1T, gbf, nullptr, 2048, 4096, 1024);
  gemm_nt64<1><<<dim3(16, 16), 256, 0, stream>>>(gbf, fc2T, d_out, x1, 2048, 1024, 4096);

  ln_bf16<<<2048, 256, 0, stream>>>((const float*)d_out, plnb, pln_g, pln_b);
  pair_head<<<2048, 256, 0, stream>>>(plnb, w1T, w2, xpi);
  pair_update<<<49152, 256, 0, stream>>>(x_pair, xpi, oc, (float*)d_out + 2097152);
}

// Round 4
// 367.200 us; speedup vs baseline: 1.1484x; 1.1484x over previous
//
#include <hip/hip_runtime.h>
#include <math.h>

// Shapes (fixed): L=512 B=4 D=1024 H=16 DH=64 FF=4096 HP=32 K=256, LK=768

typedef __bf16 bf16x8 __attribute__((ext_vector_type(8)));
typedef float f32x4 __attribute__((ext_vector_type(4)));

__device__ __forceinline__ unsigned short f2bf(float f) {
  unsigned u = __float_as_uint(f);
  u = (u + 0x7fffu + ((u >> 16) & 1u)) >> 16;
  return (unsigned short)u;
}
__device__ __forceinline__ float bf2f(unsigned short s) {
  return __uint_as_float(((unsigned)s) << 16);
}

__device__ __forceinline__ void gload_lds16(const void* g, void* l) {
  __builtin_amdgcn_global_load_lds(
      (__attribute__((address_space(1))) void*)g,
      (__attribute__((address_space(3))) void*)l, 16, 0, 0);
}

// ------------- ALL weight transposes f32 -> bf16 in one launch ---------------
// wq/wk/wv -> qkvT (3x 1024x1024), wo -> woT, fc1 -> fc1T (4096x1024),
// fc2 -> fc2T (1024x4096)
__global__ __launch_bounds__(256) void transpose_all(
    const float* __restrict__ wq, const float* __restrict__ wk, const float* __restrict__ wv,
    const float* __restrict__ wo, const float* __restrict__ fc1, const float* __restrict__ fc2,
    unsigned short* __restrict__ qkvT, unsigned short* __restrict__ woT,
    unsigned short* __restrict__ fc1T, unsigned short* __restrict__ fc2T) {
  int id = blockIdx.x;
  const float* W; unsigned short* WT; int Kd, Nd, n0, k0;
  if (id < 3072) {            // wq, wk, wv
    int which = id >> 10, lid = id & 1023;
    W = which == 0 ? wq : (which == 1 ? wk : wv);
    WT = qkvT + (long)which * 1024 * 1024;
    Kd = 1024; Nd = 1024; n0 = (lid & 31) * 32; k0 = (lid >> 5) * 32;
  } else if (id < 4096) {     // wo
    int lid = id - 3072;
    W = wo; WT = woT; Kd = 1024; Nd = 1024;
    n0 = (lid & 31) * 32; k0 = (lid >> 5) * 32;
  } else if (id < 8192) {     // fc1 (K=1024, N=4096)
    int lid = id - 4096;
    W = fc1; WT = fc1T; Kd = 1024; Nd = 4096;
    n0 = (lid & 127) * 32; k0 = (lid >> 7) * 32;
  } else {                    // fc2 (K=4096, N=1024)
    int lid = id - 8192;
    W = fc2; WT = fc2T; Kd = 4096; Nd = 1024;
    n0 = (lid & 31) * 32; k0 = (lid >> 5) * 32;
  }
  __shared__ float tile[32][33];
  const int tx = threadIdx.x, ty = threadIdx.y;  // 32 x 8
#pragma unroll
  for (int i = 0; i < 32; i += 8)
    tile[ty + i][tx] = W[(long)(k0 + ty + i) * Nd + n0 + tx];
  __syncthreads();
#pragma unroll
  for (int i = 0; i < 32; i += 8)
    WT[(long)(n0 + ty + i) * Kd + k0 + tx] = f2bf(tile[tx][ty + i]);
}

// ---------------- LayerNorm (f32 in, bf16 out), row = 1024 -------------------
__global__ __launch_bounds__(256) void ln_bf16(
    const float* __restrict__ X, unsigned short* __restrict__ Y,
    const float* __restrict__ g, const float* __restrict__ bb) {
  const int row = blockIdx.x, t = threadIdx.x;
  const float* xr = X + (long)row * 1024;
  float v[4]; float s = 0.f, ss = 0.f;
#pragma unroll
  for (int i = 0; i < 4; i++) { v[i] = xr[t + 256 * i]; s += v[i]; ss += v[i] * v[i]; }
#pragma unroll
  for (int o = 32; o > 0; o >>= 1) { s += __shfl_down(s, o); ss += __shfl_down(ss, o); }
  __shared__ float red[8];
  const int wave = t >> 6, lane = t & 63;
  if (lane == 0) { red[wave] = s; red[4 + wave] = ss; }
  __syncthreads();
  s = red[0] + red[1] + red[2] + red[3];
  ss = red[4] + red[5] + red[6] + red[7];
  const float mean = s * (1.f / 1024.f);
  const float rstd = rsqrtf(ss * (1.f / 1024.f) - mean * mean + 1e-5f);
#pragma unroll
  for (int i = 0; i < 4; i++) {
    const int c = t + 256 * i;
    Y[(long)row * 1024 + c] = f2bf((v[i] - mean) * rstd * g[c] + bb[c]);
  }
}

// -------- gather expanded rows of kv_src (bf16), rows [2048, 3072) -----------
__global__ __launch_bounds__(256) void gather_kv(unsigned short* kv, const int* __restrict__ oc) {
  int idx = blockIdx.x * 256 + threadIdx.x;  // 1024 rows * 256 ushort4 = 262144
  int col4 = idx & 255;
  int r = idx >> 8;
  int j = r >> 2, b = r & 3;
  int src = oc[b * 256 + j] * 4 + b;
  ((ushort4*)kv)[((512 + j) * 4 + b) * 256 + col4] = ((const ushort4*)kv)[src * 256 + col4];
}

// ---------------- MFMA bf16 NT GEMM, 128x128 tile, BK=32 ---------------------
// EPI: 0 = f32 out, 1 = f32 out + R, 2 = bf16 gelu(out), 3 = bf16 out
template <int EPI>
__global__ __launch_bounds__(256) void gemm_nt(
    const unsigned short* __restrict__ A, const unsigned short* __restrict__ BT,
    void* __restrict__ Cout, const float* __restrict__ R, int M, int N, int Kd) {
  __shared__ __align__(16) unsigned short As[128 * 32];
  __shared__ __align__(16) unsigned short Bs[128 * 32];
  const int t = threadIdx.x;
  const int wave = t >> 6, lane = t & 63;
  const int m0 = blockIdx.y * 128, n0 = blockIdx.x * 128;
  const int wr = wave >> 1, wc = wave & 1;
  const int lr = lane & 15, lg = lane >> 4;

  f32x4 acc[4][4] = {};

  const int srow = 32 * wave + (lane >> 2);
  const int schunk = (lane & 3) * 8;
  const unsigned short* Ag = A + (long)(m0 + srow) * Kd + schunk;
  const unsigned short* Bg = BT + (long)(n0 + srow) * Kd + schunk;
  unsigned short* AsW = &As[(32 * wave) * 32];
  unsigned short* BsW = &Bs[(32 * wave) * 32];

  for (int k0 = 0; k0 < Kd; k0 += 32) {
    __syncthreads();
    gload_lds16(Ag + k0, AsW);
    gload_lds16(Ag + k0 + 16 * (long)Kd, AsW + 16 * 32);
    gload_lds16(Bg + k0, BsW);
    gload_lds16(Bg + k0 + 16 * (long)Kd, BsW + 16 * 32);
    asm volatile("s_waitcnt vmcnt(0)" ::: "memory");
    __syncthreads();

    bf16x8 af[4], bfr[4];
#pragma unroll
    for (int mf = 0; mf < 4; mf++)
      af[mf] = *(const bf16x8*)&As[(64 * wr + 16 * mf + lr) * 32 + lg * 8];
#pragma unroll
    for (int nf = 0; nf < 4; nf++)
      bfr[nf] = *(const bf16x8*)&Bs[(64 * wc + 16 * nf + lr) * 32 + lg * 8];
#pragma unroll
    for (int mf = 0; mf < 4; mf++)
#pragma unroll
      for (int nf = 0; nf < 4; nf++)
        acc[mf][nf] = __builtin_amdgcn_mfma_f32_16x16x32_bf16(af[mf], bfr[nf], acc[mf][nf], 0, 0, 0);
  }

#pragma unroll
  for (int mf = 0; mf < 4; mf++)
#pragma unroll
    for (int nf = 0; nf < 4; nf++)
#pragma unroll
      for (int r = 0; r < 4; r++) {
        const int row = m0 + 64 * wr + 16 * mf + 4 * lg + r;
        const int col = n0 + 64 * wc + 16 * nf + lr;
        const long off = (long)row * N + col;
        float v = acc[mf][nf][r];
        if constexpr (EPI == 1) {
          ((float*)Cout)[off] = v + R[off];
        } else if constexpr (EPI == 2) {
          float gl = 0.5f * v * (1.0f + erff(v * 0.70710678118654752f));
          ((unsigned short*)Cout)[off] = f2bf(gl);
        } else if constexpr (EPI == 3) {
          ((unsigned short*)Cout)[off] = f2bf(v);
        } else {
          ((float*)Cout)[off] = v;
        }
      }
}

// ---------------- RoPE + split to per-head layouts (bf16 QKV in) -------------
// qb:  [bh][512][64] bf16, scaled by 1/8.   kbh: [bh][768][64] bf16.
__global__ __launch_bounds__(256) void rope_split2(
    const unsigned short* __restrict__ QKV, const int* __restrict__ pos_ids,
    const int* __restrict__ oc,
    unsigned short* __restrict__ qb, unsigned short* __restrict__ kbh) {
  int idx = blockIdx.x * 256 + threadIdx.x;  // 1048576 + 1572864
  bool isq = idx < 1048576;
  int rp = isq ? idx : idx - 1048576;
  int p = rp & 511;
  int row = rp >> 9;
  int hh = p >> 5, dp = p & 31;
  int s = row >> 2, b = row & 3;
  int pos = isq ? pos_ids[b * 512 + s]
                : ((s < 512) ? pos_ids[b * 512 + s]
                             : pos_ids[b * 512 + oc[b * 256 + s - 512]]);
  const unsigned short* src = QKV + (long)row * 3072 + (isq ? 0 : 1024) + hh * 64 + dp;
  float x1 = bf2f(src[0]), x2 = bf2f(src[32]);
  float invf = exp2f((float)dp * -0.41524101186091903f);  // 10000^(-dp/32)
  float ang = (float)pos * invf;
  float sn = sinf(ang), cs = cosf(ang);
  float o1 = x1 * cs - x2 * sn, o2 = x1 * sn + x2 * cs;
  if (isq) {
    unsigned short* dst = qb + ((long)(b * 16 + hh) * 512 + s) * 64 + dp;
    dst[0] = f2bf(o1 * 0.125f); dst[32] = f2bf(o2 * 0.125f);
  } else {
    unsigned short* dst = kbh + ((long)(b * 16 + hh) * 768 + s) * 64 + dp;
    dst[0] = f2bf(o1); dst[32] = f2bf(o2);
  }
}

// ---------------- V: QKV bf16 -> vth bf16 transposed [bh][64 d][768 key] -----
__global__ __launch_bounds__(256) void v_transpose(
    const unsigned short* __restrict__ QKV, unsigned short* __restrict__ vth) {
  const int kt = blockIdx.x, bh = blockIdx.y;
  const int b = bh >> 4, h = bh & 15;
  __shared__ unsigned short tile[64][72];
  const int t = threadIdx.x;
  const int key = t >> 2, c = t & 3;
  const unsigned short* src = QKV + ((long)(kt * 64 + key) * 4 + b) * 3072 + 2048 + h * 64 + c * 16;
#pragma unroll
  for (int j = 0; j < 16; j++) tile[c * 16 + j][key] = src[j];
  __syncthreads();
  const int d = t >> 2;
  unsigned short* dst = vth + ((long)bh * 64 + d) * 768 + kt * 64 + c * 16;
  *(uint4*)dst = *(const uint4*)&tile[d][c * 16];
  *(uint4*)(dst + 8) = *(const uint4*)&tile[d][c * 16 + 8];
}

// ---------------- MFMA flash attention: block = (b,h, 64 queries) ------------
__global__ __launch_bounds__(256) void att_mfma(
    const unsigned short* __restrict__ qb, const unsigned short* __restrict__ kbh,
    const unsigned short* __restrict__ vth,
    const unsigned char* __restrict__ pad_mask, const unsigned char* __restrict__ exp_mask,
    unsigned short* __restrict__ o_bf) {
  const int bh = blockIdx.y, b = bh >> 4, h = bh & 15;
  const int q0 = blockIdx.x * 64;
  const int t = threadIdx.x, wave = t >> 6, lane = t & 63;
  const int lr = lane & 15, lg = lane >> 4;

  __shared__ __align__(16) unsigned short Qs[64][72];
  __shared__ __align__(16) unsigned short Ks[64][72];
  __shared__ __align__(16) unsigned short Vs[64][72];   // VT tile: [d][key]
  __shared__ __align__(16) unsigned short Ps[4][16][72];
  __shared__ float maskAdd[768];

  {  // stage Q once
    const int row = t >> 2, c = t & 3;
    const uint4* src = (const uint4*)(qb + ((long)bh * 512 + q0 + row) * 64 + c * 16);
    *(uint4*)&Qs[row][c * 16] = src[0];
    *(uint4*)&Qs[row][c * 16 + 8] = src[1];
  }
  for (int i = t; i < 768; i += 256)
    maskAdd[i] = ((i < 512) ? pad_mask[b * 512 + i] : exp_mask[b * 256 + i - 512]) ? -1e9f : 0.f;
  __syncthreads();

  const bf16x8 aq0 = *(const bf16x8*)&Qs[wave * 16 + lr][lg * 8];
  const bf16x8 aq1 = *(const bf16x8*)&Qs[wave * 16 + lr][32 + lg * 8];

  float m_run[4] = {-1e30f, -1e30f, -1e30f, -1e30f};
  float l_run[4] = {0.f, 0.f, 0.f, 0.f};
  f32x4 Oacc[4] = {};

  for (int kt = 0; kt < 12; ++kt) {
    __syncthreads();
    {  // stage K tile and VT tile
      const int row = t >> 2, c = t & 3;
      const uint4* ksrc = (const uint4*)(kbh + ((long)bh * 768 + kt * 64 + row) * 64 + c * 16);
      *(uint4*)&Ks[row][c * 16] = ksrc[0];
      *(uint4*)&Ks[row][c * 16 + 8] = ksrc[1];
      const uint4* vsrc = (const uint4*)(vth + ((long)bh * 64 + row) * 768 + kt * 64 + c * 16);
      *(uint4*)&Vs[row][c * 16] = vsrc[0];
      *(uint4*)&Vs[row][c * 16 + 8] = vsrc[1];
    }
    __syncthreads();

    // QK^T: S[16 q][64 key] per wave
    float sv[4][4];
#pragma unroll
    for (int nf = 0; nf < 4; nf++) {
      f32x4 z = {};
      bf16x8 b0 = *(const bf16x8*)&Ks[nf * 16 + lr][lg * 8];
      bf16x8 b1 = *(const bf16x8*)&Ks[nf * 16 + lr][32 + lg * 8];
      z = __builtin_amdgcn_mfma_f32_16x16x32_bf16(aq0, b0, z, 0, 0, 0);
      z = __builtin_amdgcn_mfma_f32_16x16x32_bf16(aq1, b1, z, 0, 0, 0);
      float ma = maskAdd[kt * 64 + nf * 16 + lr];
#pragma unroll
      for (int r = 0; r < 4; r++) sv[nf][r] = z[r] + ma;
    }
    // online softmax (row = lg*4+r within wave's 16)
    float mnew[4], scale[4], rs[4];
#pragma unroll
    for (int r = 0; r < 4; r++) {
      float tm = fmaxf(fmaxf(sv[0][r], sv[1][r]), fmaxf(sv[2][r], sv[3][r]));
      tm = fmaxf(tm, __shfl_xor(tm, 1));
      tm = fmaxf(tm, __shfl_xor(tm, 2));
      tm = fmaxf(tm, __shfl_xor(tm, 4));
      tm = fmaxf(tm, __shfl_xor(tm, 8));
      mnew[r] = fmaxf(m_run[r], tm);
      scale[r] = __expf(m_run[r] - mnew[r]);
      m_run[r] = mnew[r];
      rs[r] = 0.f;
    }
#pragma unroll
    for (int nf = 0; nf < 4; nf++)
#pragma unroll
      for (int r = 0; r < 4; r++) {
        float p = __expf(sv[nf][r] - mnew[r]);
        rs[r] += p;
        Ps[wave][lg * 4 + r][nf * 16 + lr] = f2bf(p);
      }
#pragma unroll
    for (int r = 0; r < 4; r++) {
      float x = rs[r];
      x += __shfl_xor(x, 1); x += __shfl_xor(x, 2);
      x += __shfl_xor(x, 4); x += __shfl_xor(x, 8);
      l_run[r] = l_run[r] * scale[r] + x;
#pragma unroll
      for (int nf = 0; nf < 4; nf++) Oacc[nf][r] *= scale[r];
    }
    // PV: O[16 q][64 d] += P @ V
    bf16x8 ap0 = *(const bf16x8*)&Ps[wave][lr][lg * 8];
    bf16x8 ap1 = *(const bf16x8*)&Ps[wave][lr][32 + lg * 8];
#pragma unroll
    for (int nf = 0; nf < 4; nf++) {
      bf16x8 b0 = *(const bf16x8*)&Vs[nf * 16 + lr][lg * 8];
      bf16x8 b1 = *(const bf16x8*)&Vs[nf * 16 + lr][32 + lg * 8];
      Oacc[nf] = __builtin_amdgcn_mfma_f32_16x16x32_bf16(ap0, b0, Oacc[nf], 0, 0, 0);
      Oacc[nf] = __builtin_amdgcn_mfma_f32_16x16x32_bf16(ap1, b1, Oacc[nf], 0, 0, 0);
    }
  }

#pragma unroll
  for (int r = 0; r < 4; r++) {
    float inv = 1.0f / l_run[r];
    int l = q0 + wave * 16 + lg * 4 + r;
#pragma unroll
    for (int nf = 0; nf < 4; nf++)
      o_bf[(((long)l * 4 + b) * 16 + h) * 64 + nf * 16 + lr] = f2bf(Oacc[nf][r] * inv);
  }
}

// ---------------- pair head: LN'd x @ w1 -> silu -> @ w2 ---------------------
// w1 f32 [1024][64]: lanes c=0..63 read contiguous 256B -> coalesced.
__global__ __launch_bounds__(256) void pair_head(
    const unsigned short* __restrict__ pln, const float* __restrict__ w1,
    const float* __restrict__ w2, float* __restrict__ xpi) {
  const int row = blockIdx.x, t = threadIdx.x;
  __shared__ float red[64][4];
  __shared__ float s1[64];
  const int c = t & 63, qt = t >> 6;
  const unsigned short* xr = pln + (long)row * 1024;
  float acc = 0.f;
  for (int k = qt * 256; k < qt * 256 + 256; k++)
    acc += bf2f(xr[k]) * w1[k * 64 + c];
  red[c][qt] = acc;
  __syncthreads();
  if (t < 64) {
    float v = red[t][0] + red[t][1] + red[t][2] + red[t][3];
    s1[t] = v / (1.f + __expf(-v));  // silu
  }
  __syncthreads();
  if (t < 32) {
    float o = 0.f;
    for (int k = 0; k < 64; k++) o += s1[k] * w2[k * 32 + t];
    xpi[(long)row * 32 + t] = o;
  }
}

// ------------ x_pair += outer(x_p_i, x_p_j) with inline oc gather ------------
__global__ __launch_bounds__(256) void pair_update(
    const float* __restrict__ x_pair, const float* __restrict__ xpi,
    const int* __restrict__ oc, float* __restrict__ out) {
  int idx4 = blockIdx.x * 256 + threadIdx.x;  // 12582912 float4s
  int h4 = idx4 & 7;
  int lkb = idx4 >> 3;
  int b = lkb & 3;
  int lk = lkb >> 2;
  int kk = lk % 768;
  int l = lk / 768;
  int src = (kk < 512) ? kk : oc[b * 256 + kk - 512];
  float4 pv = ((const float4*)x_pair)[idx4];
  float4 a = ((const float4*)xpi)[(l * 4 + b) * 8 + h4];
  float4 bb = ((const float4*)xpi)[(src * 4 + b) * 8 + h4];
  float4 o;
  o.x = pv.x + a.x * bb.x; o.y = pv.y + a.y * bb.y;
  o.z = pv.z + a.z * bb.z; o.w = pv.w + a.w * bb.w;
  ((float4*)out)[idx4] = o;
}

// =============================== launcher ====================================
extern "C" void kernel_launch(void* const* d_in, const int* in_sizes, int n_in,
                              void* d_out, int out_size, void* d_ws, size_t ws_size,
                              hipStream_t stream) {
  const float* x        = (const float*)d_in[0];
  const float* x_pair   = (const float*)d_in[1];
  const unsigned char* pad_mask = (const unsigned char*)d_in[2];
  const unsigned char* exp_mask = (const unsigned char*)d_in[3];
  const int* pos_ids    = (const int*)d_in[4];
  const int* oc         = (const int*)d_in[5];
  const float* wq  = (const float*)d_in[6];
  const float* wk  = (const float*)d_in[7];
  const float* wv  = (const float*)d_in[8];
  const float* wo  = (const float*)d_in[9];
  const float* fc1 = (const float*)d_in[10];
  const float* fc2 = (const float*)d_in[11];
  const float* tln_g = (const float*)d_in[12];
  const float* tln_b = (const float*)d_in[13];
  const float* mln_g = (const float*)d_in[14];
  const float* mln_b = (const float*)d_in[15];
  const float* pln_g = (const float*)d_in[16];
  const float* pln_b = (const float*)d_in[17];
  const float* w1 = (const float*)d_in[18];
  const float* w2 = (const float*)d_in[19];

  char* wsp = (char*)d_ws;
  size_t off = 0;
  auto alloc = [&](size_t bytes) -> void* {
    void* p = wsp + off;
    off = (off + bytes + 255) & ~(size_t)255;
    return p;
  };
  unsigned short* qkvT = (unsigned short*)alloc(3072LL * 1024 * 2);
  unsigned short* woT  = (unsigned short*)alloc(1024LL * 1024 * 2);
  unsigned short* fc1T = (unsigned short*)alloc(4096LL * 1024 * 2);
  unsigned short* fc2T = (unsigned short*)alloc(1024LL * 4096 * 2);
  unsigned short* kvb  = (unsigned short*)alloc(3072LL * 1024 * 2);
  unsigned short* QKVb = (unsigned short*)alloc(3072LL * 3072 * 2);
  unsigned short* qb   = (unsigned short*)alloc(64LL * 512 * 64 * 2);
  unsigned short* kbh  = (unsigned short*)alloc(64LL * 768 * 64 * 2);
  unsigned short* vth  = (unsigned short*)alloc(64LL * 64 * 768 * 2);
  unsigned short* obf  = (unsigned short*)alloc(2048LL * 1024 * 2);
  float* x1            = (float*)alloc(2048LL * 1024 * 4);
  unsigned short* h2   = (unsigned short*)alloc(2048LL * 1024 * 2);
  unsigned short* gbf  = (unsigned short*)alloc(2048LL * 4096 * 2);
  unsigned short* plnb = (unsigned short*)alloc(2048LL * 1024 * 2);
  float* xpi           = (float*)alloc(2048LL * 32 * 4);
  (void)ws_size; (void)in_sizes; (void)n_in; (void)out_size;

  dim3 tb(32, 8);
  transpose_all<<<12288, tb, 0, stream>>>(wq, wk, wv, wo, fc1, fc2,
                                          qkvT, woT, fc1T, fc2T);

  ln_bf16<<<2048, 256, 0, stream>>>(x, kvb, tln_g, tln_b);
  gather_kv<<<1024, 256, 0, stream>>>(kvb, oc);

  gemm_nt<3><<<dim3(24, 24), 256, 0, stream>>>(kvb, qkvT, QKVb, nullptr, 3072, 3072, 1024);

  rope_split2<<<10240, 256, 0, stream>>>(QKVb, pos_ids, oc, qb, kbh);
  v_transpose<<<dim3(12, 64), 256, 0, stream>>>(QKVb, vth);

  att_mfma<<<dim3(8, 64), 256, 0, stream>>>(qb, kbh, vth, pad_mask, exp_mask, obf);

  gemm_nt<1><<<dim3(8, 16), 256, 0, stream>>>(obf, woT, x1, x, 2048, 1024, 1024);

  ln_bf16<<<2048, 256, 0, stream>>>(x1, h2, mln_g, mln_b);
  gemm_nt<2><<<dim3(32, 16), 256, 0, stream>>>(h2, fc1T, gbf, nullptr, 2048, 4096, 1024);
  gemm_nt<1><<<dim3(8, 16), 256, 0, stream>>>(gbf, fc2T, d_out, x1, 2048, 1024, 4096);

  ln_bf16<<<2048, 256, 0, stream>>>((const float*)d_out, plnb, pln_g, pln_b);
  pair_head<<<2048, 256, 0, stream>>>(plnb, w1, w2, xpi);
  pair_update<<<49152, 256, 0, stream>>>(x_pair, xpi, oc, (float*)d_out + 2097152);
}

// Round 5
// 324.927 us; speedup vs baseline: 1.2978x; 1.1301x over previous
//
#include <hip/hip_runtime.h>
#include <math.h>

// Shapes (fixed): L=512 B=4 D=1024 H=16 DH=64 FF=4096 HP=32 K=256, LK=768

typedef __bf16 bf16x8 __attribute__((ext_vector_type(8)));
typedef float f32x4 __attribute__((ext_vector_type(4)));

__device__ __forceinline__ unsigned short f2bf(float f) {
  unsigned u = __float_as_uint(f);
  u = (u + 0x7fffu + ((u >> 16) & 1u)) >> 16;
  return (unsigned short)u;
}
__device__ __forceinline__ float bf2f(unsigned short s) {
  return __uint_as_float(((unsigned)s) << 16);
}

__device__ __forceinline__ void gload_lds16(const void* g, void* l) {
  __builtin_amdgcn_global_load_lds(
      (__attribute__((address_space(1))) void*)g,
      (__attribute__((address_space(3))) void*)l, 16, 0, 0);
}

// ------------- ALL weight transposes f32 -> bf16 in one launch ---------------
__global__ __launch_bounds__(256) void transpose_all(
    const float* __restrict__ wq, const float* __restrict__ wk, const float* __restrict__ wv,
    const float* __restrict__ wo, const float* __restrict__ fc1, const float* __restrict__ fc2,
    unsigned short* __restrict__ qkvT, unsigned short* __restrict__ woT,
    unsigned short* __restrict__ fc1T, unsigned short* __restrict__ fc2T) {
  int id = blockIdx.x;
  const float* W; unsigned short* WT; int Kd, Nd, n0, k0;
  if (id < 3072) {            // wq, wk, wv
    int which = id >> 10, lid = id & 1023;
    W = which == 0 ? wq : (which == 1 ? wk : wv);
    WT = qkvT + (long)which * 1024 * 1024;
    Kd = 1024; Nd = 1024; n0 = (lid & 31) * 32; k0 = (lid >> 5) * 32;
  } else if (id < 4096) {     // wo
    int lid = id - 3072;
    W = wo; WT = woT; Kd = 1024; Nd = 1024;
    n0 = (lid & 31) * 32; k0 = (lid >> 5) * 32;
  } else if (id < 8192) {     // fc1 (K=1024, N=4096)
    int lid = id - 4096;
    W = fc1; WT = fc1T; Kd = 1024; Nd = 4096;
    n0 = (lid & 127) * 32; k0 = (lid >> 7) * 32;
  } else {                    // fc2 (K=4096, N=1024)
    int lid = id - 8192;
    W = fc2; WT = fc2T; Kd = 4096; Nd = 1024;
    n0 = (lid & 31) * 32; k0 = (lid >> 5) * 32;
  }
  __shared__ float tile[32][33];
  const int tx = threadIdx.x, ty = threadIdx.y;  // 32 x 8
#pragma unroll
  for (int i = 0; i < 32; i += 8)
    tile[ty + i][tx] = W[(long)(k0 + ty + i) * Nd + n0 + tx];
  __syncthreads();
#pragma unroll
  for (int i = 0; i < 32; i += 8)
    WT[(long)(n0 + ty + i) * Kd + k0 + tx] = f2bf(tile[tx][ty + i]);
}

// ---------------- LayerNorm (f32 in, bf16 out), row = 1024 -------------------
__global__ __launch_bounds__(256) void ln_bf16(
    const float* __restrict__ X, unsigned short* __restrict__ Y,
    const float* __restrict__ g, const float* __restrict__ bb) {
  const int row = blockIdx.x, t = threadIdx.x;
  const float* xr = X + (long)row * 1024;
  float v[4]; float s = 0.f, ss = 0.f;
#pragma unroll
  for (int i = 0; i < 4; i++) { v[i] = xr[t + 256 * i]; s += v[i]; ss += v[i] * v[i]; }
#pragma unroll
  for (int o = 32; o > 0; o >>= 1) { s += __shfl_down(s, o); ss += __shfl_down(ss, o); }
  __shared__ float red[8];
  const int wave = t >> 6, lane = t & 63;
  if (lane == 0) { red[wave] = s; red[4 + wave] = ss; }
  __syncthreads();
  s = red[0] + red[1] + red[2] + red[3];
  ss = red[4] + red[5] + red[6] + red[7];
  const float mean = s * (1.f / 1024.f);
  const float rstd = rsqrtf(ss * (1.f / 1024.f) - mean * mean + 1e-5f);
#pragma unroll
  for (int i = 0; i < 4; i++) {
    const int c = t + 256 * i;
    Y[(long)row * 1024 + c] = f2bf((v[i] - mean) * rstd * g[c] + bb[c]);
  }
}

// ------- fused: v = p0 + p1 + R; Xout = v; Y = bf16(LN(v)) -------------------
__global__ __launch_bounds__(256) void red_ln(
    const float* __restrict__ p0, const float* __restrict__ p1,
    const float* __restrict__ R, float* __restrict__ Xout,
    const float* __restrict__ g, const float* __restrict__ bb,
    unsigned short* __restrict__ Y) {
  const int row = blockIdx.x, t = threadIdx.x;
  const long base = (long)row * 1024;
  float v[4]; float s = 0.f, ss = 0.f;
#pragma unroll
  for (int i = 0; i < 4; i++) {
    const int c = t + 256 * i;
    float val = p0[base + c] + p1[base + c] + R[base + c];
    Xout[base + c] = val;
    v[i] = val; s += val; ss += val * val;
  }
#pragma unroll
  for (int o = 32; o > 0; o >>= 1) { s += __shfl_down(s, o); ss += __shfl_down(ss, o); }
  __shared__ float red[8];
  const int wave = t >> 6, lane = t & 63;
  if (lane == 0) { red[wave] = s; red[4 + wave] = ss; }
  __syncthreads();
  s = red[0] + red[1] + red[2] + red[3];
  ss = red[4] + red[5] + red[6] + red[7];
  const float mean = s * (1.f / 1024.f);
  const float rstd = rsqrtf(ss * (1.f / 1024.f) - mean * mean + 1e-5f);
#pragma unroll
  for (int i = 0; i < 4; i++) {
    const int c = t + 256 * i;
    Y[base + c] = f2bf((v[i] - mean) * rstd * g[c] + bb[c]);
  }
}

// -------- gather expanded rows of kv_src (bf16), rows [2048, 3072) -----------
__global__ __launch_bounds__(256) void gather_kv(unsigned short* kv, const int* __restrict__ oc) {
  int idx = blockIdx.x * 256 + threadIdx.x;  // 1024 rows * 256 ushort4 = 262144
  int col4 = idx & 255;
  int r = idx >> 8;
  int j = r >> 2, b = r & 3;
  int src = oc[b * 256 + j] * 4 + b;
  ((ushort4*)kv)[((512 + j) * 4 + b) * 256 + col4] = ((const ushort4*)kv)[src * 256 + col4];
}

// ---------------- MFMA bf16 NT GEMM, 128x128 tile, BK=32 ---------------------
// EPI: 0 = f32 out, 1 = f32 out + R, 2 = bf16 gelu(out), 3 = bf16 out
template <int EPI>
__global__ __launch_bounds__(256) void gemm_nt(
    const unsigned short* __restrict__ A, const unsigned short* __restrict__ BT,
    void* __restrict__ Cout, const float* __restrict__ R, int M, int N, int Kd) {
  __shared__ __align__(16) unsigned short As[128 * 32];
  __shared__ __align__(16) unsigned short Bs[128 * 32];
  const int t = threadIdx.x;
  const int wave = t >> 6, lane = t & 63;
  const int m0 = blockIdx.y * 128, n0 = blockIdx.x * 128;
  const int wr = wave >> 1, wc = wave & 1;
  const int lr = lane & 15, lg = lane >> 4;

  f32x4 acc[4][4] = {};

  const int srow = 32 * wave + (lane >> 2);
  const int schunk = (lane & 3) * 8;
  const unsigned short* Ag = A + (long)(m0 + srow) * Kd + schunk;
  const unsigned short* Bg = BT + (long)(n0 + srow) * Kd + schunk;
  unsigned short* AsW = &As[(32 * wave) * 32];
  unsigned short* BsW = &Bs[(32 * wave) * 32];

  for (int k0 = 0; k0 < Kd; k0 += 32) {
    __syncthreads();
    gload_lds16(Ag + k0, AsW);
    gload_lds16(Ag + k0 + 16 * (long)Kd, AsW + 16 * 32);
    gload_lds16(Bg + k0, BsW);
    gload_lds16(Bg + k0 + 16 * (long)Kd, BsW + 16 * 32);
    asm volatile("s_waitcnt vmcnt(0)" ::: "memory");
    __syncthreads();

    bf16x8 af[4], bfr[4];
#pragma unroll
    for (int mf = 0; mf < 4; mf++)
      af[mf] = *(const bf16x8*)&As[(64 * wr + 16 * mf + lr) * 32 + lg * 8];
#pragma unroll
    for (int nf = 0; nf < 4; nf++)
      bfr[nf] = *(const bf16x8*)&Bs[(64 * wc + 16 * nf + lr) * 32 + lg * 8];
#pragma unroll
    for (int mf = 0; mf < 4; mf++)
#pragma unroll
      for (int nf = 0; nf < 4; nf++)
        acc[mf][nf] = __builtin_amdgcn_mfma_f32_16x16x32_bf16(af[mf], bfr[nf], acc[mf][nf], 0, 0, 0);
  }

#pragma unroll
  for (int mf = 0; mf < 4; mf++)
#pragma unroll
    for (int nf = 0; nf < 4; nf++)
#pragma unroll
      for (int r = 0; r < 4; r++) {
        const int row = m0 + 64 * wr + 16 * mf + 4 * lg + r;
        const int col = n0 + 64 * wc + 16 * nf + lr;
        const long off = (long)row * N + col;
        float v = acc[mf][nf][r];
        if constexpr (EPI == 1) {
          ((float*)Cout)[off] = v + R[off];
        } else if constexpr (EPI == 2) {
          float gl = 0.5f * v * (1.0f + erff(v * 0.70710678118654752f));
          ((unsigned short*)Cout)[off] = f2bf(gl);
        } else if constexpr (EPI == 3) {
          ((unsigned short*)Cout)[off] = f2bf(v);
        } else {
          ((float*)Cout)[off] = v;
        }
      }
}

// ------------ split-K=2 variant: partial f32 C per blockIdx.z ----------------
__global__ __launch_bounds__(256) void gemm_nt_splitk(
    const unsigned short* __restrict__ A, const unsigned short* __restrict__ BT,
    float* __restrict__ Cp, int M, int N, int Kd) {
  const int kh = Kd >> 1;
  const long kbase = (long)blockIdx.z * kh;
  const unsigned short* A2 = A + kbase;
  const unsigned short* B2 = BT + kbase;
  float* Cz = Cp + (long)blockIdx.z * M * N;

  __shared__ __align__(16) unsigned short As[128 * 32];
  __shared__ __align__(16) unsigned short Bs[128 * 32];
  const int t = threadIdx.x;
  const int wave = t >> 6, lane = t & 63;
  const int m0 = blockIdx.y * 128, n0 = blockIdx.x * 128;
  const int wr = wave >> 1, wc = wave & 1;
  const int lr = lane & 15, lg = lane >> 4;

  f32x4 acc[4][4] = {};

  const int srow = 32 * wave + (lane >> 2);
  const int schunk = (lane & 3) * 8;
  const unsigned short* Ag = A2 + (long)(m0 + srow) * Kd + schunk;
  const unsigned short* Bg = B2 + (long)(n0 + srow) * Kd + schunk;
  unsigned short* AsW = &As[(32 * wave) * 32];
  unsigned short* BsW = &Bs[(32 * wave) * 32];

  for (int k0 = 0; k0 < kh; k0 += 32) {
    __syncthreads();
    gload_lds16(Ag + k0, AsW);
    gload_lds16(Ag + k0 + 16 * (long)Kd, AsW + 16 * 32);
    gload_lds16(Bg + k0, BsW);
    gload_lds16(Bg + k0 + 16 * (long)Kd, BsW + 16 * 32);
    asm volatile("s_waitcnt vmcnt(0)" ::: "memory");
    __syncthreads();

    bf16x8 af[4], bfr[4];
#pragma unroll
    for (int mf = 0; mf < 4; mf++)
      af[mf] = *(const bf16x8*)&As[(64 * wr + 16 * mf + lr) * 32 + lg * 8];
#pragma unroll
    for (int nf = 0; nf < 4; nf++)
      bfr[nf] = *(const bf16x8*)&Bs[(64 * wc + 16 * nf + lr) * 32 + lg * 8];
#pragma unroll
    for (int mf = 0; mf < 4; mf++)
#pragma unroll
      for (int nf = 0; nf < 4; nf++)
        acc[mf][nf] = __builtin_amdgcn_mfma_f32_16x16x32_bf16(af[mf], bfr[nf], acc[mf][nf], 0, 0, 0);
  }

#pragma unroll
  for (int mf = 0; mf < 4; mf++)
#pragma unroll
    for (int nf = 0; nf < 4; nf++)
#pragma unroll
      for (int r = 0; r < 4; r++) {
        const int row = m0 + 64 * wr + 16 * mf + 4 * lg + r;
        const int col = n0 + 64 * wc + 16 * nf + lr;
        Cz[(long)row * N + col] = acc[mf][nf][r];
      }
}

// ---------------- RoPE + split to per-head layouts (bf16 QKV in) -------------
__global__ __launch_bounds__(256) void rope_split2(
    const unsigned short* __restrict__ QKV, const int* __restrict__ pos_ids,
    const int* __restrict__ oc,
    unsigned short* __restrict__ qb, unsigned short* __restrict__ kbh) {
  int idx = blockIdx.x * 256 + threadIdx.x;  // 1048576 + 1572864
  bool isq = idx < 1048576;
  int rp = isq ? idx : idx - 1048576;
  int p = rp & 511;
  int row = rp >> 9;
  int hh = p >> 5, dp = p & 31;
  int s = row >> 2, b = row & 3;
  int pos = isq ? pos_ids[b * 512 + s]
                : ((s < 512) ? pos_ids[b * 512 + s]
                             : pos_ids[b * 512 + oc[b * 256 + s - 512]]);
  const unsigned short* src = QKV + (long)row * 3072 + (isq ? 0 : 1024) + hh * 64 + dp;
  float x1 = bf2f(src[0]), x2 = bf2f(src[32]);
  float invf = exp2f((float)dp * -0.41524101186091903f);  // 10000^(-dp/32)
  float ang = (float)pos * invf;
  float sn = sinf(ang), cs = cosf(ang);
  float o1 = x1 * cs - x2 * sn, o2 = x1 * sn + x2 * cs;
  if (isq) {
    unsigned short* dst = qb + ((long)(b * 16 + hh) * 512 + s) * 64 + dp;
    dst[0] = f2bf(o1 * 0.125f); dst[32] = f2bf(o2 * 0.125f);
  } else {
    unsigned short* dst = kbh + ((long)(b * 16 + hh) * 768 + s) * 64 + dp;
    dst[0] = f2bf(o1); dst[32] = f2bf(o2);
  }
}

// ---------------- V: QKV bf16 -> vth bf16 transposed [bh][64 d][768 key] -----
__global__ __launch_bounds__(256) void v_transpose(
    const unsigned short* __restrict__ QKV, unsigned short* __restrict__ vth) {
  const int kt = blockIdx.x, bh = blockIdx.y;
  const int b = bh >> 4, h = bh & 15;
  __shared__ unsigned short tile[64][72];
  const int t = threadIdx.x;
  const int key = t >> 2, c = t & 3;
  const unsigned short* src = QKV + ((long)(kt * 64 + key) * 4 + b) * 3072 + 2048 + h * 64 + c * 16;
#pragma unroll
  for (int j = 0; j < 16; j++) tile[c * 16 + j][key] = src[j];
  __syncthreads();
  const int d = t >> 2;
  unsigned short* dst = vth + ((long)bh * 64 + d) * 768 + kt * 64 + c * 16;
  *(uint4*)dst = *(const uint4*)&tile[d][c * 16];
  *(uint4*)(dst + 8) = *(const uint4*)&tile[d][c * 16 + 8];
}

// -------- MFMA flash attention: block = (b,h, 128 queries), 8 waves ----------
__global__ __launch_bounds__(512) void att_mfma(
    const unsigned short* __restrict__ qb, const unsigned short* __restrict__ kbh,
    const unsigned short* __restrict__ vth,
    const unsigned char* __restrict__ pad_mask, const unsigned char* __restrict__ exp_mask,
    unsigned short* __restrict__ o_bf) {
  const int bh = blockIdx.y, b = bh >> 4, h = bh & 15;
  const int q0 = blockIdx.x * 128;
  const int t = threadIdx.x, wave = t >> 6, lane = t & 63;
  const int lr = lane & 15, lg = lane >> 4;

  __shared__ __align__(16) unsigned short Ks[64][72];
  __shared__ __align__(16) unsigned short Vs[64][72];   // VT tile: [d][key]
  __shared__ __align__(16) unsigned short Ps[8][16][72];
  __shared__ float maskAdd[768];

  for (int i = t; i < 768; i += 512)
    maskAdd[i] = ((i < 512) ? pad_mask[b * 512 + i] : exp_mask[b * 256 + i - 512]) ? -1e9f : 0.f;

  // Q fragments direct from global (once per block)
  const unsigned short* qrow = qb + ((long)bh * 512 + q0 + wave * 16 + lr) * 64;
  const bf16x8 aq0 = *(const bf16x8*)(qrow + lg * 8);
  const bf16x8 aq1 = *(const bf16x8*)(qrow + 32 + lg * 8);

  float m_run[4] = {-1e30f, -1e30f, -1e30f, -1e30f};
  float l_run[4] = {0.f, 0.f, 0.f, 0.f};
  f32x4 Oacc[4] = {};

  const int srow = t >> 3, sc = (t & 7) * 8;  // 512 threads = 64 rows x 8 chunks
  for (int kt = 0; kt < 12; ++kt) {
    __syncthreads();
    *(uint4*)&Ks[srow][sc] =
        *(const uint4*)(kbh + ((long)bh * 768 + kt * 64 + srow) * 64 + sc);
    *(uint4*)&Vs[srow][sc] =
        *(const uint4*)(vth + ((long)bh * 64 + srow) * 768 + kt * 64 + sc);
    __syncthreads();

    // QK^T: S[16 q][64 key] per wave
    float sv[4][4];
#pragma unroll
    for (int nf = 0; nf < 4; nf++) {
      f32x4 z = {};
      bf16x8 b0 = *(const bf16x8*)&Ks[nf * 16 + lr][lg * 8];
      bf16x8 b1 = *(const bf16x8*)&Ks[nf * 16 + lr][32 + lg * 8];
      z = __builtin_amdgcn_mfma_f32_16x16x32_bf16(aq0, b0, z, 0, 0, 0);
      z = __builtin_amdgcn_mfma_f32_16x16x32_bf16(aq1, b1, z, 0, 0, 0);
      float ma = maskAdd[kt * 64 + nf * 16 + lr];
#pragma unroll
      for (int r = 0; r < 4; r++) sv[nf][r] = z[r] + ma;
    }
    // online softmax (row = lg*4+r within wave's 16)
    float mnew[4], scale[4], rs[4];
#pragma unroll
    for (int r = 0; r < 4; r++) {
      float tm = fmaxf(fmaxf(sv[0][r], sv[1][r]), fmaxf(sv[2][r], sv[3][r]));
      tm = fmaxf(tm, __shfl_xor(tm, 1));
      tm = fmaxf(tm, __shfl_xor(tm, 2));
      tm = fmaxf(tm, __shfl_xor(tm, 4));
      tm = fmaxf(tm, __shfl_xor(tm, 8));
      mnew[r] = fmaxf(m_run[r], tm);
      scale[r] = __expf(m_run[r] - mnew[r]);
      m_run[r] = mnew[r];
      rs[r] = 0.f;
    }
#pragma unroll
    for (int nf = 0; nf < 4; nf++)
#pragma unroll
      for (int r = 0; r < 4; r++) {
        float p = __expf(sv[nf][r] - mnew[r]);
        rs[r] += p;
        Ps[wave][lg * 4 + r][nf * 16 + lr] = f2bf(p);
      }
#pragma unroll
    for (int r = 0; r < 4; r++) {
      float x = rs[r];
      x += __shfl_xor(x, 1); x += __shfl_xor(x, 2);
      x += __shfl_xor(x, 4); x += __shfl_xor(x, 8);
      l_run[r] = l_run[r] * scale[r] + x;
#pragma unroll
      for (int nf = 0; nf < 4; nf++) Oacc[nf][r] *= scale[r];
    }
    // PV: O[16 q][64 d] += P @ V   (Ps is per-wave; no barrier needed)
    bf16x8 ap0 = *(const bf16x8*)&Ps[wave][lr][lg * 8];
    bf16x8 ap1 = *(const bf16x8*)&Ps[wave][lr][32 + lg * 8];
#pragma unroll
    for (int nf = 0; nf < 4; nf++) {
      bf16x8 b0 = *(const bf16x8*)&Vs[nf * 16 + lr][lg * 8];
      bf16x8 b1 = *(const bf16x8*)&Vs[nf * 16 + lr][32 + lg * 8];
      Oacc[nf] = __builtin_amdgcn_mfma_f32_16x16x32_bf16(ap0, b0, Oacc[nf], 0, 0, 0);
      Oacc[nf] = __builtin_amdgcn_mfma_f32_16x16x32_bf16(ap1, b1, Oacc[nf], 0, 0, 0);
    }
  }

#pragma unroll
  for (int r = 0; r < 4; r++) {
    float inv = 1.0f / l_run[r];
    int l = q0 + wave * 16 + lg * 4 + r;
#pragma unroll
    for (int nf = 0; nf < 4; nf++)
      o_bf[(((long)l * 4 + b) * 16 + h) * 64 + nf * 16 + lr] = f2bf(Oacc[nf][r] * inv);
  }
}

// ---------------- pair head: LN'd x @ w1 -> silu -> @ w2 ---------------------
__global__ __launch_bounds__(256) void pair_head(
    const unsigned short* __restrict__ pln, const float* __restrict__ w1,
    const float* __restrict__ w2, float* __restrict__ xpi) {
  const int row = blockIdx.x, t = threadIdx.x;
  __shared__ float red[64][4];
  __shared__ float s1[64];
  const int c = t & 63, qt = t >> 6;
  const unsigned short* xr = pln + (long)row * 1024;
  float acc = 0.f;
  for (int k = qt * 256; k < qt * 256 + 256; k++)
    acc += bf2f(xr[k]) * w1[k * 64 + c];
  red[c][qt] = acc;
  __syncthreads();
  if (t < 64) {
    float v = red[t][0] + red[t][1] + red[t][2] + red[t][3];
    s1[t] = v / (1.f + __expf(-v));  // silu
  }
  __syncthreads();
  if (t < 32) {
    float o = 0.f;
    for (int k = 0; k < 64; k++) o += s1[k] * w2[k * 32 + t];
    xpi[(long)row * 32 + t] = o;
  }
}

// ------------ x_pair += outer(x_p_i, x_p_j) with inline oc gather ------------
__global__ __launch_bounds__(256) void pair_update(
    const float* __restrict__ x_pair, const float* __restrict__ xpi,
    const int* __restrict__ oc, float* __restrict__ out) {
  int idx4 = blockIdx.x * 256 + threadIdx.x;  // 12582912 float4s
  int h4 = idx4 & 7;
  int lkb = idx4 >> 3;
  int b = lkb & 3;
  int lk = lkb >> 2;
  int kk = lk % 768;
  int l = lk / 768;
  int src = (kk < 512) ? kk : oc[b * 256 + kk - 512];
  float4 pv = ((const float4*)x_pair)[idx4];
  float4 a = ((const float4*)xpi)[(l * 4 + b) * 8 + h4];
  float4 bb = ((const float4*)xpi)[(src * 4 + b) * 8 + h4];
  float4 o;
  o.x = pv.x + a.x * bb.x; o.y = pv.y + a.y * bb.y;
  o.z = pv.z + a.z * bb.z; o.w = pv.w + a.w * bb.w;
  ((float4*)out)[idx4] = o;
}

// =============================== launcher ====================================
extern "C" void kernel_launch(void* const* d_in, const int* in_sizes, int n_in,
                              void* d_out, int out_size, void* d_ws, size_t ws_size,
                              hipStream_t stream) {
  const float* x        = (const float*)d_in[0];
  const float* x_pair   = (const float*)d_in[1];
  const unsigned char* pad_mask = (const unsigned char*)d_in[2];
  const unsigned char* exp_mask = (const unsigned char*)d_in[3];
  const int* pos_ids    = (const int*)d_in[4];
  const int* oc         = (const int*)d_in[5];
  const float* wq  = (const float*)d_in[6];
  const float* wk  = (const float*)d_in[7];
  const float* wv  = (const float*)d_in[8];
  const float* wo  = (const float*)d_in[9];
  const float* fc1 = (const float*)d_in[10];
  const float* fc2 = (const float*)d_in[11];
  const float* tln_g = (const float*)d_in[12];
  const float* tln_b = (const float*)d_in[13];
  const float* mln_g = (const float*)d_in[14];
  const float* mln_b = (const float*)d_in[15];
  const float* pln_g = (const float*)d_in[16];
  const float* pln_b = (const float*)d_in[17];
  const float* w1 = (const float*)d_in[18];
  const float* w2 = (const float*)d_in[19];

  char* wsp = (char*)d_ws;
  size_t off = 0;
  auto alloc = [&](size_t bytes) -> void* {
    void* p = wsp + off;
    off = (off + bytes + 255) & ~(size_t)255;
    return p;
  };
  unsigned short* qkvT = (unsigned short*)alloc(3072LL * 1024 * 2);
  unsigned short* woT  = (unsigned short*)alloc(1024LL * 1024 * 2);
  unsigned short* fc1T = (unsigned short*)alloc(4096LL * 1024 * 2);
  unsigned short* fc2T = (unsigned short*)alloc(1024LL * 4096 * 2);
  unsigned short* kvb  = (unsigned short*)alloc(3072LL * 1024 * 2);
  unsigned short* QKVb = (unsigned short*)alloc(3072LL * 3072 * 2);
  unsigned short* qb   = (unsigned short*)alloc(64LL * 512 * 64 * 2);
  unsigned short* kbh  = (unsigned short*)alloc(64LL * 768 * 64 * 2);
  unsigned short* vth  = (unsigned short*)alloc(64LL * 64 * 768 * 2);
  unsigned short* obf  = (unsigned short*)alloc(2048LL * 1024 * 2);
  float* x1            = (float*)alloc(2048LL * 1024 * 4);
  unsigned short* h2   = (unsigned short*)alloc(2048LL * 1024 * 2);
  unsigned short* gbf  = (unsigned short*)alloc(2048LL * 4096 * 2);
  unsigned short* plnb = (unsigned short*)alloc(2048LL * 1024 * 2);
  float* xpi           = (float*)alloc(2048LL * 32 * 4);
  float* pp            = (float*)alloc(2LL * 2048 * 1024 * 4);  // split-K partials
  (void)ws_size; (void)in_sizes; (void)n_in; (void)out_size;

  dim3 tb(32, 8);
  transpose_all<<<12288, tb, 0, stream>>>(wq, wk, wv, wo, fc1, fc2,
                                          qkvT, woT, fc1T, fc2T);

  ln_bf16<<<2048, 256, 0, stream>>>(x, kvb, tln_g, tln_b);
  gather_kv<<<1024, 256, 0, stream>>>(kvb, oc);

  gemm_nt<3><<<dim3(24, 24), 256, 0, stream>>>(kvb, qkvT, QKVb, nullptr, 3072, 3072, 1024);

  rope_split2<<<10240, 256, 0, stream>>>(QKVb, pos_ids, oc, qb, kbh);
  v_transpose<<<dim3(12, 64), 256, 0, stream>>>(QKVb, vth);

  att_mfma<<<dim3(4, 64), 512, 0, stream>>>(qb, kbh, vth, pad_mask, exp_mask, obf);

  // x1 = x + attn_out @ wo  (split-K=2 + fused reduce+residual+LN -> h2)
  gemm_nt_splitk<<<dim3(8, 16, 2), 256, 0, stream>>>(obf, woT, pp, 2048, 1024, 1024);
  red_ln<<<2048, 256, 0, stream>>>(pp, pp + 2097152, x, x1, mln_g, mln_b, h2);

  gemm_nt<2><<<dim3(32, 16), 256, 0, stream>>>(h2, fc1T, gbf, nullptr, 2048, 4096, 1024);

  // x = x1 + gelu @ fc2  (split-K=2 + fused reduce+residual+LN -> plnb)
  gemm_nt_splitk<<<dim3(8, 16, 2), 256, 0, stream>>>(gbf, fc2T, pp, 2048, 1024, 4096);
  red_ln<<<2048, 256, 0, stream>>>(pp, pp + 2097152, x1, (float*)d_out, pln_g, pln_b, plnb);

  pair_head<<<2048, 256, 0, stream>>>(plnb, w1, w2, xpi);
  pair_update<<<49152, 256, 0, stream>>>(x_pair, xpi, oc, (float*)d_out + 2097152);
}

// Round 6
// 318.151 us; speedup vs baseline: 1.3254x; 1.0213x over previous
//
#include <hip/hip_runtime.h>
#include <math.h>

// Shapes (fixed): L=512 B=4 D=1024 H=16 DH=64 FF=4096 HP=32 K=256, LK=768

typedef __bf16 bf16x8 __attribute__((ext_vector_type(8)));
typedef float f32x4 __attribute__((ext_vector_type(4)));

__device__ __forceinline__ unsigned short f2bf(float f) {
  unsigned u = __float_as_uint(f);
  u = (u + 0x7fffu + ((u >> 16) & 1u)) >> 16;
  return (unsigned short)u;
}
__device__ __forceinline__ float bf2f(unsigned short s) {
  return __uint_as_float(((unsigned)s) << 16);
}

__device__ __forceinline__ void gload_lds16(const void* g, void* l) {
  __builtin_amdgcn_global_load_lds(
      (__attribute__((address_space(1))) void*)g,
      (__attribute__((address_space(3))) void*)l, 16, 0, 0);
}

// ------------- ALL weight transposes f32 -> bf16, 64k x 32n tiles ------------
__global__ __launch_bounds__(256) void transpose_all(
    const float* __restrict__ wq, const float* __restrict__ wk, const float* __restrict__ wv,
    const float* __restrict__ wo, const float* __restrict__ fc1, const float* __restrict__ fc2,
    unsigned short* __restrict__ qkvT, unsigned short* __restrict__ woT,
    unsigned short* __restrict__ fc1T, unsigned short* __restrict__ fc2T) {
  int id = blockIdx.x;
  const float* W; unsigned short* WT; int Kd, Nd, n0, k0;
  if (id < 2048) {            // wq, wk, wv, wo : 512 blocks each (16 kt x 32 nt)
    int which = id >> 9, lid = id & 511;
    W = which == 0 ? wq : (which == 1 ? wk : (which == 2 ? wv : wo));
    WT = which < 3 ? qkvT + (long)which * 1024 * 1024 : woT;
    Kd = 1024; Nd = 1024;
    k0 = (lid >> 5) * 64; n0 = (lid & 31) * 32;
  } else if (id < 4096) {     // fc1 (K=1024, N=4096): 16 kt x 128 nt
    int lid = id - 2048;
    W = fc1; WT = fc1T; Kd = 1024; Nd = 4096;
    k0 = (lid >> 7) * 64; n0 = (lid & 127) * 32;
  } else {                    // fc2 (K=4096, N=1024): 64 kt x 32 nt
    int lid = id - 4096;
    W = fc2; WT = fc2T; Kd = 4096; Nd = 1024;
    k0 = (lid >> 5) * 64; n0 = (lid & 31) * 32;
  }
  __shared__ float tile[64][33];
  const int tx = threadIdx.x, ty = threadIdx.y;  // 32 x 8
#pragma unroll
  for (int j = 0; j < 64; j += 8)
    tile[ty + j][tx] = W[(long)(k0 + ty + j) * Nd + n0 + tx];
  __syncthreads();
#pragma unroll
  for (int i = 0; i < 32; i += 8) {
    ushort2 o;
    o.x = f2bf(tile[2 * tx][ty + i]);
    o.y = f2bf(tile[2 * tx + 1][ty + i]);
    *(ushort2*)&WT[(long)(n0 + ty + i) * Kd + k0 + 2 * tx] = o;
  }
}

// ---------------- LayerNorm (f32 in, bf16 out), row = 1024 -------------------
__global__ __launch_bounds__(256) void ln_bf16(
    const float* __restrict__ X, unsigned short* __restrict__ Y,
    const float* __restrict__ g, const float* __restrict__ bb) {
  const int row = blockIdx.x, t = threadIdx.x;
  const float* xr = X + (long)row * 1024;
  float v[4]; float s = 0.f, ss = 0.f;
#pragma unroll
  for (int i = 0; i < 4; i++) { v[i] = xr[t + 256 * i]; s += v[i]; ss += v[i] * v[i]; }
#pragma unroll
  for (int o = 32; o > 0; o >>= 1) { s += __shfl_down(s, o); ss += __shfl_down(ss, o); }
  __shared__ float red[8];
  const int wave = t >> 6, lane = t & 63;
  if (lane == 0) { red[wave] = s; red[4 + wave] = ss; }
  __syncthreads();
  s = red[0] + red[1] + red[2] + red[3];
  ss = red[4] + red[5] + red[6] + red[7];
  const float mean = s * (1.f / 1024.f);
  const float rstd = rsqrtf(ss * (1.f / 1024.f) - mean * mean + 1e-5f);
#pragma unroll
  for (int i = 0; i < 4; i++) {
    const int c = t + 256 * i;
    Y[(long)row * 1024 + c] = f2bf((v[i] - mean) * rstd * g[c] + bb[c]);
  }
}

// ------- fused: v = p0 + p1 + R; Xout = v; Y = bf16(LN(v)) -------------------
__global__ __launch_bounds__(256) void red_ln(
    const float* __restrict__ p0, const float* __restrict__ p1,
    const float* __restrict__ R, float* __restrict__ Xout,
    const float* __restrict__ g, const float* __restrict__ bb,
    unsigned short* __restrict__ Y) {
  const int row = blockIdx.x, t = threadIdx.x;
  const long base = (long)row * 1024;
  float v[4]; float s = 0.f, ss = 0.f;
#pragma unroll
  for (int i = 0; i < 4; i++) {
    const int c = t + 256 * i;
    float val = p0[base + c] + p1[base + c] + R[base + c];
    Xout[base + c] = val;
    v[i] = val; s += val; ss += val * val;
  }
#pragma unroll
  for (int o = 32; o > 0; o >>= 1) { s += __shfl_down(s, o); ss += __shfl_down(ss, o); }
  __shared__ float red[8];
  const int wave = t >> 6, lane = t & 63;
  if (lane == 0) { red[wave] = s; red[4 + wave] = ss; }
  __syncthreads();
  s = red[0] + red[1] + red[2] + red[3];
  ss = red[4] + red[5] + red[6] + red[7];
  const float mean = s * (1.f / 1024.f);
  const float rstd = rsqrtf(ss * (1.f / 1024.f) - mean * mean + 1e-5f);
#pragma unroll
  for (int i = 0; i < 4; i++) {
    const int c = t + 256 * i;
    Y[base + c] = f2bf((v[i] - mean) * rstd * g[c] + bb[c]);
  }
}

// ------- fused: reduce+residual+LN (f32) + pair head (silu @ w2) -------------
__global__ __launch_bounds__(256) void red_ln_pair(
    const float* __restrict__ p0, const float* __restrict__ p1,
    const float* __restrict__ R, float* __restrict__ Xout,
    const float* __restrict__ g, const float* __restrict__ bb,
    const float* __restrict__ w1, const float* __restrict__ w2,
    float* __restrict__ xpi) {
  const int row = blockIdx.x, t = threadIdx.x;
  const long base = (long)row * 1024;
  __shared__ float lnrow[1024];
  __shared__ float red[8];
  __shared__ float red2[64][4];
  __shared__ float s1[64];
  float v[4]; float s = 0.f, ss = 0.f;
#pragma unroll
  for (int i = 0; i < 4; i++) {
    const int c = t + 256 * i;
    float val = p0[base + c] + p1[base + c] + R[base + c];
    Xout[base + c] = val;
    v[i] = val; s += val; ss += val * val;
  }
#pragma unroll
  for (int o = 32; o > 0; o >>= 1) { s += __shfl_down(s, o); ss += __shfl_down(ss, o); }
  const int wave = t >> 6, lane = t & 63;
  if (lane == 0) { red[wave] = s; red[4 + wave] = ss; }
  __syncthreads();
  s = red[0] + red[1] + red[2] + red[3];
  ss = red[4] + red[5] + red[6] + red[7];
  const float mean = s * (1.f / 1024.f);
  const float rstd = rsqrtf(ss * (1.f / 1024.f) - mean * mean + 1e-5f);
#pragma unroll
  for (int i = 0; i < 4; i++) {
    const int c = t + 256 * i;
    lnrow[c] = (v[i] - mean) * rstd * g[c] + bb[c];
  }
  __syncthreads();
  // pair head: acc over 1024 k for 64 outputs
  const int c = t & 63, qt = t >> 6;
  float acc = 0.f;
  for (int k = qt * 256; k < qt * 256 + 256; k++)
    acc += lnrow[k] * w1[k * 64 + c];
  red2[c][qt] = acc;
  __syncthreads();
  if (t < 64) {
    float vv = red2[t][0] + red2[t][1] + red2[t][2] + red2[t][3];
    s1[t] = vv / (1.f + __expf(-vv));  // silu
  }
  __syncthreads();
  if (t < 32) {
    float o = 0.f;
    for (int k = 0; k < 64; k++) o += s1[k] * w2[k * 32 + t];
    xpi[(long)row * 32 + t] = o;
  }
}

// -------- gather expanded rows of kv_src (bf16), rows [2048, 3072) -----------
__global__ __launch_bounds__(256) void gather_kv(unsigned short* kv, const int* __restrict__ oc) {
  int idx = blockIdx.x * 256 + threadIdx.x;  // 1024 rows * 256 ushort4 = 262144
  int col4 = idx & 255;
  int r = idx >> 8;
  int j = r >> 2, b = r & 3;
  int src = oc[b * 256 + j] * 4 + b;
  ((ushort4*)kv)[((512 + j) * 4 + b) * 256 + col4] = ((const ushort4*)kv)[src * 256 + col4];
}

// ---------------- MFMA bf16 NT GEMM, 128x128 tile, BK=32 ---------------------
// EPI: 0 = f32 out, 1 = f32 out + R, 2 = bf16 gelu(out), 3 = bf16 out
template <int EPI>
__global__ __launch_bounds__(256) void gemm_nt(
    const unsigned short* __restrict__ A, const unsigned short* __restrict__ BT,
    void* __restrict__ Cout, const float* __restrict__ R, int M, int N, int Kd) {
  __shared__ __align__(16) unsigned short As[128 * 32];
  __shared__ __align__(16) unsigned short Bs[128 * 32];
  const int t = threadIdx.x;
  const int wave = t >> 6, lane = t & 63;
  const int m0 = blockIdx.y * 128, n0 = blockIdx.x * 128;
  const int wr = wave >> 1, wc = wave & 1;
  const int lr = lane & 15, lg = lane >> 4;

  f32x4 acc[4][4] = {};

  const int srow = 32 * wave + (lane >> 2);
  const int schunk = (lane & 3) * 8;
  const unsigned short* Ag = A + (long)(m0 + srow) * Kd + schunk;
  const unsigned short* Bg = BT + (long)(n0 + srow) * Kd + schunk;
  unsigned short* AsW = &As[(32 * wave) * 32];
  unsigned short* BsW = &Bs[(32 * wave) * 32];

  for (int k0 = 0; k0 < Kd; k0 += 32) {
    __syncthreads();
    gload_lds16(Ag + k0, AsW);
    gload_lds16(Ag + k0 + 16 * (long)Kd, AsW + 16 * 32);
    gload_lds16(Bg + k0, BsW);
    gload_lds16(Bg + k0 + 16 * (long)Kd, BsW + 16 * 32);
    asm volatile("s_waitcnt vmcnt(0)" ::: "memory");
    __syncthreads();

    bf16x8 af[4], bfr[4];
#pragma unroll
    for (int mf = 0; mf < 4; mf++)
      af[mf] = *(const bf16x8*)&As[(64 * wr + 16 * mf + lr) * 32 + lg * 8];
#pragma unroll
    for (int nf = 0; nf < 4; nf++)
      bfr[nf] = *(const bf16x8*)&Bs[(64 * wc + 16 * nf + lr) * 32 + lg * 8];
#pragma unroll
    for (int mf = 0; mf < 4; mf++)
#pragma unroll
      for (int nf = 0; nf < 4; nf++)
        acc[mf][nf] = __builtin_amdgcn_mfma_f32_16x16x32_bf16(af[mf], bfr[nf], acc[mf][nf], 0, 0, 0);
  }

#pragma unroll
  for (int mf = 0; mf < 4; mf++)
#pragma unroll
    for (int nf = 0; nf < 4; nf++)
#pragma unroll
      for (int r = 0; r < 4; r++) {
        const int row = m0 + 64 * wr + 16 * mf + 4 * lg + r;
        const int col = n0 + 64 * wc + 16 * nf + lr;
        const long off = (long)row * N + col;
        float v = acc[mf][nf][r];
        if constexpr (EPI == 1) {
          ((float*)Cout)[off] = v + R[off];
        } else if constexpr (EPI == 2) {
          float gl = 0.5f * v * (1.0f + erff(v * 0.70710678118654752f));
          ((unsigned short*)Cout)[off] = f2bf(gl);
        } else if constexpr (EPI == 3) {
          ((unsigned short*)Cout)[off] = f2bf(v);
        } else {
          ((float*)Cout)[off] = v;
        }
      }
}

// -------- QKV GEMM: 1D grid, dead Q tiles (m>=16, n<8) skipped ---------------
__global__ __launch_bounds__(256) void gemm_qkv(
    const unsigned short* __restrict__ A, const unsigned short* __restrict__ BT,
    unsigned short* __restrict__ Cout) {
  constexpr int N = 3072, Kd = 1024;
  int bid = blockIdx.x;
  int mt, nt;
  if (bid < 384) { mt = bid / 24; nt = bid % 24; }
  else { int rem = bid - 384; mt = 16 + (rem >> 4); nt = 8 + (rem & 15); }
  const int m0 = mt * 128, n0 = nt * 128;

  __shared__ __align__(16) unsigned short As[128 * 32];
  __shared__ __align__(16) unsigned short Bs[128 * 32];
  const int t = threadIdx.x;
  const int wave = t >> 6, lane = t & 63;
  const int wr = wave >> 1, wc = wave & 1;
  const int lr = lane & 15, lg = lane >> 4;

  f32x4 acc[4][4] = {};

  const int srow = 32 * wave + (lane >> 2);
  const int schunk = (lane & 3) * 8;
  const unsigned short* Ag = A + (long)(m0 + srow) * Kd + schunk;
  const unsigned short* Bg = BT + (long)(n0 + srow) * Kd + schunk;
  unsigned short* AsW = &As[(32 * wave) * 32];
  unsigned short* BsW = &Bs[(32 * wave) * 32];

  for (int k0 = 0; k0 < Kd; k0 += 32) {
    __syncthreads();
    gload_lds16(Ag + k0, AsW);
    gload_lds16(Ag + k0 + 16 * (long)Kd, AsW + 16 * 32);
    gload_lds16(Bg + k0, BsW);
    gload_lds16(Bg + k0 + 16 * (long)Kd, BsW + 16 * 32);
    asm volatile("s_waitcnt vmcnt(0)" ::: "memory");
    __syncthreads();

    bf16x8 af[4], bfr[4];
#pragma unroll
    for (int mf = 0; mf < 4; mf++)
      af[mf] = *(const bf16x8*)&As[(64 * wr + 16 * mf + lr) * 32 + lg * 8];
#pragma unroll
    for (int nf = 0; nf < 4; nf++)
      bfr[nf] = *(const bf16x8*)&Bs[(64 * wc + 16 * nf + lr) * 32 + lg * 8];
#pragma unroll
    for (int mf = 0; mf < 4; mf++)
#pragma unroll
      for (int nf = 0; nf < 4; nf++)
        acc[mf][nf] = __builtin_amdgcn_mfma_f32_16x16x32_bf16(af[mf], bfr[nf], acc[mf][nf], 0, 0, 0);
  }

#pragma unroll
  for (int mf = 0; mf < 4; mf++)
#pragma unroll
    for (int nf = 0; nf < 4; nf++)
#pragma unroll
      for (int r = 0; r < 4; r++) {
        const int row = m0 + 64 * wr + 16 * mf + 4 * lg + r;
        const int col = n0 + 64 * wc + 16 * nf + lr;
        Cout[(long)row * N + col] = f2bf(acc[mf][nf][r]);
      }
}

// ------------ split-K=2 variant: partial f32 C per blockIdx.z ----------------
__global__ __launch_bounds__(256) void gemm_nt_splitk(
    const unsigned short* __restrict__ A, const unsigned short* __restrict__ BT,
    float* __restrict__ Cp, int M, int N, int Kd) {
  const int kh = Kd >> 1;
  const long kbase = (long)blockIdx.z * kh;
  const unsigned short* A2 = A + kbase;
  const unsigned short* B2 = BT + kbase;
  float* Cz = Cp + (long)blockIdx.z * M * N;

  __shared__ __align__(16) unsigned short As[128 * 32];
  __shared__ __align__(16) unsigned short Bs[128 * 32];
  const int t = threadIdx.x;
  const int wave = t >> 6, lane = t & 63;
  const int m0 = blockIdx.y * 128, n0 = blockIdx.x * 128;
  const int wr = wave >> 1, wc = wave & 1;
  const int lr = lane & 15, lg = lane >> 4;

  f32x4 acc[4][4] = {};

  const int srow = 32 * wave + (lane >> 2);
  const int schunk = (lane & 3) * 8;
  const unsigned short* Ag = A2 + (long)(m0 + srow) * Kd + schunk;
  const unsigned short* Bg = B2 + (long)(n0 + srow) * Kd + schunk;
  unsigned short* AsW = &As[(32 * wave) * 32];
  unsigned short* BsW = &Bs[(32 * wave) * 32];

  for (int k0 = 0; k0 < kh; k0 += 32) {
    __syncthreads();
    gload_lds16(Ag + k0, AsW);
    gload_lds16(Ag + k0 + 16 * (long)Kd, AsW + 16 * 32);
    gload_lds16(Bg + k0, BsW);
    gload_lds16(Bg + k0 + 16 * (long)Kd, BsW + 16 * 32);
    asm volatile("s_waitcnt vmcnt(0)" ::: "memory");
    __syncthreads();

    bf16x8 af[4], bfr[4];
#pragma unroll
    for (int mf = 0; mf < 4; mf++)
      af[mf] = *(const bf16x8*)&As[(64 * wr + 16 * mf + lr) * 32 + lg * 8];
#pragma unroll
    for (int nf = 0; nf < 4; nf++)
      bfr[nf] = *(const bf16x8*)&Bs[(64 * wc + 16 * nf + lr) * 32 + lg * 8];
#pragma unroll
    for (int mf = 0; mf < 4; mf++)
#pragma unroll
      for (int nf = 0; nf < 4; nf++)
        acc[mf][nf] = __builtin_amdgcn_mfma_f32_16x16x32_bf16(af[mf], bfr[nf], acc[mf][nf], 0, 0, 0);
  }

#pragma unroll
  for (int mf = 0; mf < 4; mf++)
#pragma unroll
    for (int nf = 0; nf < 4; nf++)
#pragma unroll
      for (int r = 0; r < 4; r++) {
        const int row = m0 + 64 * wr + 16 * mf + 4 * lg + r;
        const int col = n0 + 64 * wc + 16 * nf + lr;
        Cz[(long)row * N + col] = acc[mf][nf][r];
      }
}

// ---------------- RoPE + split to per-head layouts (bf16 QKV in) -------------
__global__ __launch_bounds__(256) void rope_split2(
    const unsigned short* __restrict__ QKV, const int* __restrict__ pos_ids,
    const int* __restrict__ oc,
    unsigned short* __restrict__ qb, unsigned short* __restrict__ kbh) {
  int idx = blockIdx.x * 256 + threadIdx.x;  // 1048576 + 1572864
  bool isq = idx < 1048576;
  int rp = isq ? idx : idx - 1048576;
  int p = rp & 511;
  int row = rp >> 9;
  int hh = p >> 5, dp = p & 31;
  int s = row >> 2, b = row & 3;
  int pos = isq ? pos_ids[b * 512 + s]
                : ((s < 512) ? pos_ids[b * 512 + s]
                             : pos_ids[b * 512 + oc[b * 256 + s - 512]]);
  const unsigned short* src = QKV + (long)row * 3072 + (isq ? 0 : 1024) + hh * 64 + dp;
  float x1 = bf2f(src[0]), x2 = bf2f(src[32]);
  float invf = exp2f((float)dp * -0.41524101186091903f);  // 10000^(-dp/32)
  float ang = (float)pos * invf;
  float sn = sinf(ang), cs = cosf(ang);
  float o1 = x1 * cs - x2 * sn, o2 = x1 * sn + x2 * cs;
  if (isq) {
    unsigned short* dst = qb + ((long)(b * 16 + hh) * 512 + s) * 64 + dp;
    dst[0] = f2bf(o1 * 0.125f); dst[32] = f2bf(o2 * 0.125f);
  } else {
    unsigned short* dst = kbh + ((long)(b * 16 + hh) * 768 + s) * 64 + dp;
    dst[0] = f2bf(o1); dst[32] = f2bf(o2);
  }
}

// ---------------- V: QKV bf16 -> vth bf16 transposed [bh][64 d][768 key] -----
__global__ __launch_bounds__(256) void v_transpose(
    const unsigned short* __restrict__ QKV, unsigned short* __restrict__ vth) {
  const int kt = blockIdx.x, bh = blockIdx.y;
  const int b = bh >> 4, h = bh & 15;
  __shared__ unsigned short tile[64][72];
  const int t = threadIdx.x;
  const int key = t >> 2, c = t & 3;
  const unsigned short* src = QKV + ((long)(kt * 64 + key) * 4 + b) * 3072 + 2048 + h * 64 + c * 16;
#pragma unroll
  for (int j = 0; j < 16; j++) tile[c * 16 + j][key] = src[j];
  __syncthreads();
  const int d = t >> 2;
  unsigned short* dst = vth + ((long)bh * 64 + d) * 768 + kt * 64 + c * 16;
  *(uint4*)dst = *(const uint4*)&tile[d][c * 16];
  *(uint4*)(dst + 8) = *(const uint4*)&tile[d][c * 16 + 8];
}

// -- MFMA flash attention, barrier-free: fragments direct from global (L1/L2) -
__global__ __launch_bounds__(512) void att_mfma(
    const unsigned short* __restrict__ qb, const unsigned short* __restrict__ kbh,
    const unsigned short* __restrict__ vth,
    const unsigned char* __restrict__ pad_mask, const unsigned char* __restrict__ exp_mask,
    unsigned short* __restrict__ o_bf) {
  const int bh = blockIdx.y, b = bh >> 4, h = bh & 15;
  const int q0 = blockIdx.x * 128;
  const int t = threadIdx.x, wave = t >> 6, lane = t & 63;
  const int lr = lane & 15, lg = lane >> 4;

  __shared__ __align__(16) unsigned short Ps[8][16][72];
  __shared__ float maskAdd[768];

  for (int i = t; i < 768; i += 512)
    maskAdd[i] = ((i < 512) ? pad_mask[b * 512 + i] : exp_mask[b * 256 + i - 512]) ? -1e9f : 0.f;

  // Q fragments direct from global (once per block)
  const unsigned short* qrow = qb + ((long)bh * 512 + q0 + wave * 16 + lr) * 64;
  const bf16x8 aq0 = *(const bf16x8*)(qrow + lg * 8);
  const bf16x8 aq1 = *(const bf16x8*)(qrow + 32 + lg * 8);
  __syncthreads();  // maskAdd ready; no further barriers in the K-loop

  float m_run[4] = {-1e30f, -1e30f, -1e30f, -1e30f};
  float l_run[4] = {0.f, 0.f, 0.f, 0.f};
  f32x4 Oacc[4] = {};

  const unsigned short* kb0 = kbh + (long)bh * 768 * 64;
  const unsigned short* vb0 = vth + (long)bh * 64 * 768;

  for (int kt = 0; kt < 12; ++kt) {
    // QK^T: S[16 q][64 key] per wave; K fragments straight from global
    float sv[4][4];
#pragma unroll
    for (int nf = 0; nf < 4; nf++) {
      const unsigned short* kr = kb0 + (long)(kt * 64 + nf * 16 + lr) * 64;
      f32x4 z = {};
      bf16x8 b0 = *(const bf16x8*)(kr + lg * 8);
      bf16x8 b1 = *(const bf16x8*)(kr + 32 + lg * 8);
      z = __builtin_amdgcn_mfma_f32_16x16x32_bf16(aq0, b0, z, 0, 0, 0);
      z = __builtin_amdgcn_mfma_f32_16x16x32_bf16(aq1, b1, z, 0, 0, 0);
      float ma = maskAdd[kt * 64 + nf * 16 + lr];
#pragma unroll
      for (int r = 0; r < 4; r++) sv[nf][r] = z[r] + ma;
    }
    // online softmax (row = lg*4+r within wave's 16)
    float mnew[4], scale[4], rs[4];
#pragma unroll
    for (int r = 0; r < 4; r++) {
      float tm = fmaxf(fmaxf(sv[0][r], sv[1][r]), fmaxf(sv[2][r], sv[3][r]));
      tm = fmaxf(tm, __shfl_xor(tm, 1));
      tm = fmaxf(tm, __shfl_xor(tm, 2));
      tm = fmaxf(tm, __shfl_xor(tm, 4));
      tm = fmaxf(tm, __shfl_xor(tm, 8));
      mnew[r] = fmaxf(m_run[r], tm);
      scale[r] = __expf(m_run[r] - mnew[r]);
      m_run[r] = mnew[r];
      rs[r] = 0.f;
    }
#pragma unroll
    for (int nf = 0; nf < 4; nf++)
#pragma unroll
      for (int r = 0; r < 4; r++) {
        float p = __expf(sv[nf][r] - mnew[r]);
        rs[r] += p;
        Ps[wave][lg * 4 + r][nf * 16 + lr] = f2bf(p);
      }
#pragma unroll
    for (int r = 0; r < 4; r++) {
      float x = rs[r];
      x += __shfl_xor(x, 1); x += __shfl_xor(x, 2);
      x += __shfl_xor(x, 4); x += __shfl_xor(x, 8);
      l_run[r] = l_run[r] * scale[r] + x;
#pragma unroll
      for (int nf = 0; nf < 4; nf++) Oacc[nf][r] *= scale[r];
    }
    // PV: O[16 q][64 d] += P @ V ; V fragments straight from global
    bf16x8 ap0 = *(const bf16x8*)&Ps[wave][lr][lg * 8];
    bf16x8 ap1 = *(const bf16x8*)&Ps[wave][lr][32 + lg * 8];
#pragma unroll
    for (int nf = 0; nf < 4; nf++) {
      const unsigned short* vr = vb0 + (long)(nf * 16 + lr) * 768 + kt * 64;
      bf16x8 b0 = *(const bf16x8*)(vr + lg * 8);
      bf16x8 b1 = *(const bf16x8*)(vr + 32 + lg * 8);
      Oacc[nf] = __builtin_amdgcn_mfma_f32_16x16x32_bf16(ap0, b0, Oacc[nf], 0, 0, 0);
      Oacc[nf] = __builtin_amdgcn_mfma_f32_16x16x32_bf16(ap1, b1, Oacc[nf], 0, 0, 0);
    }
  }

#pragma unroll
  for (int r = 0; r < 4; r++) {
    float inv = 1.0f / l_run[r];
    int l = q0 + wave * 16 + lg * 4 + r;
#pragma unroll
    for (int nf = 0; nf < 4; nf++)
      o_bf[(((long)l * 4 + b) * 16 + h) * 64 + nf * 16 + lr] = f2bf(Oacc[nf][r] * inv);
  }
}

// ------------ x_pair += outer(x_p_i, x_p_j) with inline oc gather ------------
__global__ __launch_bounds__(256) void pair_update(
    const float* __restrict__ x_pair, const float* __restrict__ xpi,
    const int* __restrict__ oc, float* __restrict__ out) {
  int idx4 = blockIdx.x * 256 + threadIdx.x;  // 12582912 float4s
  int h4 = idx4 & 7;
  int lkb = idx4 >> 3;
  int b = lkb & 3;
  int lk = lkb >> 2;
  int kk = lk % 768;
  int l = lk / 768;
  int src = (kk < 512) ? kk : oc[b * 256 + kk - 512];
  float4 pv = ((const float4*)x_pair)[idx4];
  float4 a = ((const float4*)xpi)[(l * 4 + b) * 8 + h4];
  float4 bb = ((const float4*)xpi)[(src * 4 + b) * 8 + h4];
  float4 o;
  o.x = pv.x + a.x * bb.x; o.y = pv.y + a.y * bb.y;
  o.z = pv.z + a.z * bb.z; o.w = pv.w + a.w * bb.w;
  ((float4*)out)[idx4] = o;
}

// =============================== launcher ====================================
extern "C" void kernel_launch(void* const* d_in, const int* in_sizes, int n_in,
                              void* d_out, int out_size, void* d_ws, size_t ws_size,
                              hipStream_t stream) {
  const float* x        = (const float*)d_in[0];
  const float* x_pair   = (const float*)d_in[1];
  const unsigned char* pad_mask = (const unsigned char*)d_in[2];
  const unsigned char* exp_mask = (const unsigned char*)d_in[3];
  const int* pos_ids    = (const int*)d_in[4];
  const int* oc         = (const int*)d_in[5];
  const float* wq  = (const float*)d_in[6];
  const float* wk  = (const float*)d_in[7];
  const float* wv  = (const float*)d_in[8];
  const float* wo  = (const float*)d_in[9];
  const float* fc1 = (const float*)d_in[10];
  const float* fc2 = (const float*)d_in[11];
  const float* tln_g = (const float*)d_in[12];
  const float* tln_b = (const float*)d_in[13];
  const float* mln_g = (const float*)d_in[14];
  const float* mln_b = (const float*)d_in[15];
  const float* pln_g = (const float*)d_in[16];
  const float* pln_b = (const float*)d_in[17];
  const float* w1 = (const float*)d_in[18];
  const float* w2 = (const float*)d_in[19];

  char* wsp = (char*)d_ws;
  size_t off = 0;
  auto alloc = [&](size_t bytes) -> void* {
    void* p = wsp + off;
    off = (off + bytes + 255) & ~(size_t)255;
    return p;
  };
  unsigned short* qkvT = (unsigned short*)alloc(3072LL * 1024 * 2);
  unsigned short* woT  = (unsigned short*)alloc(1024LL * 1024 * 2);
  unsigned short* fc1T = (unsigned short*)alloc(4096LL * 1024 * 2);
  unsigned short* fc2T = (unsigned short*)alloc(1024LL * 4096 * 2);
  unsigned short* kvb  = (unsigned short*)alloc(3072LL * 1024 * 2);
  unsigned short* QKVb = (unsigned short*)alloc(3072LL * 3072 * 2);
  unsigned short* qb   = (unsigned short*)alloc(64LL * 512 * 64 * 2);
  unsigned short* kbh  = (unsigned short*)alloc(64LL * 768 * 64 * 2);
  unsigned short* vth  = (unsigned short*)alloc(64LL * 64 * 768 * 2);
  unsigned short* obf  = (unsigned short*)alloc(2048LL * 1024 * 2);
  float* x1            = (float*)alloc(2048LL * 1024 * 4);
  unsigned short* h2   = (unsigned short*)alloc(2048LL * 1024 * 2);
  unsigned short* gbf  = (unsigned short*)alloc(2048LL * 4096 * 2);
  float* xpi           = (float*)alloc(2048LL * 32 * 4);
  float* pp            = (float*)alloc(2LL * 2048 * 1024 * 4);  // split-K partials
  (void)ws_size; (void)in_sizes; (void)n_in; (void)out_size;

  dim3 tb(32, 8);
  transpose_all<<<6144, tb, 0, stream>>>(wq, wk, wv, wo, fc1, fc2,
                                         qkvT, woT, fc1T, fc2T);

  ln_bf16<<<2048, 256, 0, stream>>>(x, kvb, tln_g, tln_b);
  gather_kv<<<1024, 256, 0, stream>>>(kvb, oc);

  gemm_qkv<<<512, 256, 0, stream>>>(kvb, qkvT, QKVb);

  rope_split2<<<10240, 256, 0, stream>>>(QKVb, pos_ids, oc, qb, kbh);
  v_transpose<<<dim3(12, 64), 256, 0, stream>>>(QKVb, vth);

  att_mfma<<<dim3(4, 64), 512, 0, stream>>>(qb, kbh, vth, pad_mask, exp_mask, obf);

  // x1 = x + attn_out @ wo  (split-K=2 + fused reduce+residual+LN -> h2)
  gemm_nt_splitk<<<dim3(8, 16, 2), 256, 0, stream>>>(obf, woT, pp, 2048, 1024, 1024);
  red_ln<<<2048, 256, 0, stream>>>(pp, pp + 2097152, x, x1, mln_g, mln_b, h2);

  gemm_nt<2><<<dim3(32, 16), 256, 0, stream>>>(h2, fc1T, gbf, nullptr, 2048, 4096, 1024);

  // x = x1 + gelu @ fc2  (split-K=2 + fused reduce+residual+LN+pairhead)
  gemm_nt_splitk<<<dim3(8, 16, 2), 256, 0, stream>>>(gbf, fc2T, pp, 2048, 1024, 4096);
  red_ln_pair<<<2048, 256, 0, stream>>>(pp, pp + 2097152, x1, (float*)d_out,
                                        pln_g, pln_b, w1, w2, xpi);

  pair_update<<<49152, 256, 0, stream>>>(x_pair, xpi, oc, (float*)d_out + 2097152);
}